// Round 16
// baseline (151.794 us; speedup 1.0000x reference)
//
#include <hip/hip_runtime.h>
#include <hip/hip_bf16.h>
#include <hip/hip_fp16.h>
#include <cstdint>

// B=8, S=2048, D=256 fused attention block, fp32 in/out.
// Round 16 (= round 15 with the VGPR cap fixed): __launch_bounds__(512,2)
// capped the allocator at 128 VGPR; the 32-rows/wave kernel needs ~250 ->
// scratch spill catastrophe (WRITE_SIZE 63MB, MfmaUtil 0.35%). Now (512):
// 256-VGPR cap (implied by 512-thr co-residency), occupancy unchanged
// (LDS-limited to 1 block/CU). Everything else identical to round 15.

#define RROWS 16384
#define DD 256
#define SEQ 2048
#define NB 8
#define QBLK 256
#define KVBLK 64
#define NTILES (SEQ / KVBLK)              // 32 V s-tiles per batch

typedef _Float16 f16x8 __attribute__((ext_vector_type(8)));
typedef _Float16 f16x4 __attribute__((ext_vector_type(4)));
typedef float f32x4 __attribute__((ext_vector_type(4)));

// ---------------------------------------------------------------------------
// casts
// ---------------------------------------------------------------------------
__global__ __launch_bounds__(256) void cast_x_kernel(
    const float* __restrict__ src, _Float16* __restrict__ dst)
{
  const size_t i = ((size_t)blockIdx.x * 256 + threadIdx.x) * 8;
  float4 a = *(const float4*)&src[i];
  float4 b = *(const float4*)&src[i + 4];
  f16x8 h = { (_Float16)a.x, (_Float16)a.y, (_Float16)a.z, (_Float16)a.w,
              (_Float16)b.x, (_Float16)b.y, (_Float16)b.z, (_Float16)b.w };
  *(f16x8*)&dst[i] = h;
}

__global__ __launch_bounds__(256) void cast_w_kernel(
    const float* __restrict__ w0, const float* __restrict__ w1,
    const float* __restrict__ w2, const float* __restrict__ w3,
    _Float16* __restrict__ dst)
{
  const float* srcs[4] = {w0, w1, w2, w3};
  const float* src = srcs[blockIdx.y];
  _Float16* d = dst + (size_t)blockIdx.y * 65536;
  const size_t i = ((size_t)blockIdx.x * 256 + threadIdx.x) * 8;
  float4 a = *(const float4*)&src[i];
  float4 b = *(const float4*)&src[i + 4];
  f16x8 h = { (_Float16)a.x, (_Float16)a.y, (_Float16)a.z, (_Float16)a.w,
              (_Float16)b.x, (_Float16)b.y, (_Float16)b.z, (_Float16)b.w };
  *(f16x8*)&d[i] = h;
}

// ---------------------------------------------------------------------------
// fp16 MFMA GEMM: 64x128 tile, K=256.
// MODE 0: f32 out + res.          MODE 1: f16 row-major (Q).
// MODE 2: f16 TILED [b][s/64][256 d][64 s] with granule swizzle (V).
// MODE 3: f16 row-major with granule swizzle (K):
//         elem(r,c) -> r*256 + (((c>>3) ^ (r&7))<<3) + (c&7).
// ---------------------------------------------------------------------------
template <int MODE>
__global__ __launch_bounds__(256) void gemm16_kernel(
    const _Float16* __restrict__ X, const _Float16* __restrict__ W,
    const float* __restrict__ bias, const float* __restrict__ res,
    void* __restrict__ outv)
{
  __shared__ _Float16 smem[128 * 264];
  const int t     = threadIdx.x;
  const int lane  = t & 63;
  const int w     = t >> 6;
  const int rows0 = blockIdx.x * 64;
  const int col0  = blockIdx.y * 128;
  const int lr = lane & 15;
  const int lg = lane >> 4;

#pragma unroll
  for (int i = 0; i < 16; ++i) {
    int ch = i * 256 + t;
    int er = ch >> 5, kc = (ch & 31) * 8;
    *(f16x8*)&smem[er * 264 + kc] = *(const f16x8*)&W[(size_t)(col0 + er) * DD + kc];
  }

  f16x8 qf[8];
  {
    const _Float16* xrow = X + (size_t)(rows0 + w * 16 + lr) * DD;
#pragma unroll
    for (int ks = 0; ks < 8; ++ks)
      qf[ks] = *(const f16x8*)(xrow + ks * 32 + lg * 8);
  }
  __syncthreads();

  f32x4 acc[8];
#pragma unroll
  for (int i = 0; i < 8; ++i) acc[i] = (f32x4){0.f, 0.f, 0.f, 0.f};

#pragma unroll
  for (int ct = 0; ct < 8; ++ct)
#pragma unroll
    for (int ks = 0; ks < 8; ++ks) {
      f16x8 wf = *(const f16x8*)&smem[(ct * 16 + lr) * 264 + ks * 32 + lg * 8];
      acc[ct] = __builtin_amdgcn_mfma_f32_16x16x32_f16(qf[ks], wf, acc[ct], 0, 0, 0);
    }

  float bf[8];
#pragma unroll
  for (int ct = 0; ct < 8; ++ct) bf[ct] = bias[col0 + ct * 16 + lr];

  if constexpr (MODE == 0) {
    float* out = (float*)outv;
#pragma unroll
    for (int ct = 0; ct < 8; ++ct)
#pragma unroll
      for (int j = 0; j < 4; ++j) {
        int r = rows0 + w * 16 + lg * 4 + j;
        int c = col0 + ct * 16 + lr;
        out[(size_t)r * DD + c] = acc[ct][j] + bf[ct] + res[(size_t)r * DD + c];
      }
  } else if constexpr (MODE == 1) {
    _Float16* out = (_Float16*)outv;
#pragma unroll
    for (int ct = 0; ct < 8; ++ct)
#pragma unroll
      for (int j = 0; j < 4; ++j) {
        int r = rows0 + w * 16 + lg * 4 + j;
        out[(size_t)r * DD + col0 + ct * 16 + lr] = (_Float16)(acc[ct][j] + bf[ct]);
      }
  } else if constexpr (MODE == 3) {   // K: row-major + granule swizzle
    _Float16* out = (_Float16*)outv;
#pragma unroll
    for (int ct = 0; ct < 8; ++ct)
#pragma unroll
      for (int j = 0; j < 4; ++j) {
        int r = rows0 + w * 16 + lg * 4 + j;
        int c = col0 + ct * 16 + lr;
        out[(size_t)r * DD + (((c >> 3) ^ (r & 7)) << 3) + (c & 7)] =
            (_Float16)(acc[ct][j] + bf[ct]);
      }
  } else {  // MODE 2: tiled V^T [b][s/64][256 d][64 s] + granule swizzle
    __syncthreads();
    _Float16* T = smem;   // reuse: [128 e][72 s-pitch]
#pragma unroll
    for (int ct = 0; ct < 8; ++ct)
#pragma unroll
      for (int j = 0; j < 4; ++j)
        T[(ct * 16 + lr) * 72 + (w * 16 + lg * 4 + j)] = (_Float16)(acc[ct][j] + bf[ct]);
    __syncthreads();
    _Float16* out = (_Float16*)outv;
    const int bIdx = rows0 >> 11;
    const int tIdx = (rows0 & (SEQ - 1)) >> 6;
    _Float16* base = out + (((size_t)bIdx * NTILES + tIdx) * DD + col0) * KVBLK;
#pragma unroll
    for (int p = 0; p < 4; ++p) {
      int ch = p * 256 + t;
      int e = ch >> 3, sc = (ch & 7) * 8;          // sc multiple of 8
      int g = (sc >> 3) ^ (e & 7);                 // swizzled 16B granule
      *(f16x8*)&base[(size_t)e * KVBLK + (g << 3)] = *(const f16x8*)&T[e * 72 + sc];
    }
  }
}

// ---------------------------------------------------------------------------
// Split-K MFMA flash attention, v6b (32 q-rows per wave, full VGPR budget).
// Block = 512 thr (8 waves), each wave owns 32 q-rows (2 row-groups of 16).
// QBLK=256, KVBLK=64. Grid = 8 qtiles x nsplit x 8 batches; lid&7 = batch.
// K single-buffered LDS (raw mid-tile s_barrier; stage lands during SM+PV);
// V double-buffered (staged at tile top, full tile to land). Ps granule-
// swizzled. Each K-fragment read feeds 2 MFMAs; each V pair feeds 4.
// ---------------------------------------------------------------------------
__global__ __launch_bounds__(512) void attn_partial_kernel(
    const _Float16* __restrict__ Q, const _Float16* __restrict__ K,
    const _Float16* __restrict__ VT, _Float16* __restrict__ Op,
    float* __restrict__ Mp, float* __restrict__ Lp, int nsplit)
{
  __shared__ _Float16 Ks[KVBLK * DD];      // 32 KB single, swizzled rows 512B
  __shared__ _Float16 Vt[2][DD * KVBLK];   // 2 x 32 KB, swizzled rows 128B
  __shared__ _Float16 Ps[8][32 * 64];      // 32 KB, granule-swizzled

  const int t     = threadIdx.x;
  const int lane  = t & 63;
  const int w     = t >> 6;               // wave 0..7
  const int lid   = blockIdx.x;
  const int b     = lid & 7;              // batch == XCD slot
  const int inner = lid >> 3;
  const int lsn   = (nsplit == 4) ? 2 : 1;
  const int split = inner & (nsplit - 1);
  const int q0    = (inner >> lsn) * QBLK;
  const int ntsp  = NTILES / nsplit;      // tiles per split (8 or 16)
  const int kt0   = split * ntsp;
  const int lr    = lane & 15;
  const int lg    = lane >> 4;
  const int sw    = lr & 7;               // row-dependent granule XOR

  // Q fragments: wave's 32 rows (2 rg) x K=256
  f16x8 qf[2][8];
#pragma unroll
  for (int rg = 0; rg < 2; ++rg) {
    const _Float16* qrow =
        Q + (size_t)b * SEQ * DD + (size_t)(q0 + w * 32 + rg * 16 + lr) * DD;
#pragma unroll
    for (int ks = 0; ks < 8; ++ks)
      qf[rg][ks] = *(const f16x8*)(qrow + ks * 32 + lg * 8);
  }

  const char* Kb = (const char*)(K + (size_t)b * SEQ * DD);
  const char* Vb = (const char*)(VT + (size_t)b * NTILES * (DD * KVBLK));

  auto STAGE_K = [&](int ktAbs) {
    const char* kg = Kb + (size_t)ktAbs * (KVBLK * DD) * 2;
    char* kl = (char*)&Ks[0];
#pragma unroll
    for (int i = 0; i < 4; ++i) {
      int off = i * 8192 + t * 16;
      __builtin_amdgcn_global_load_lds((const void*)(kg + off), (void*)(kl + off),
                                       16, 0, 0);
    }
  };
  auto STAGE_V = [&](int ktAbs, int buf) {
    const char* vg = Vb + (size_t)ktAbs * (DD * KVBLK) * 2;
    char* vl = (char*)&Vt[buf][0];
#pragma unroll
    for (int i = 0; i < 4; ++i) {
      int off = i * 8192 + t * 16;
      __builtin_amdgcn_global_load_lds((const void*)(vg + off), (void*)(vl + off),
                                       16, 0, 0);
    }
  };

  f32x4 cacc[2][16];
#pragma unroll
  for (int rg = 0; rg < 2; ++rg)
#pragma unroll
    for (int i = 0; i < 16; ++i) cacc[rg][i] = (f32x4){0.f, 0.f, 0.f, 0.f};
  float mrun[2][4], lrun[2][4];
#pragma unroll
  for (int rg = 0; rg < 2; ++rg)
#pragma unroll
    for (int j = 0; j < 4; ++j) { mrun[rg][j] = -1e30f; lrun[rg][j] = 0.f; }

  STAGE_V(kt0, 0);
  STAGE_K(kt0);
  __syncthreads();                         // drain: buf0 + K ready

  int cur = 0;
  for (int kt = 0; kt < ntsp; ++kt) {
    const bool pre = (kt + 1 < ntsp);
    if (pre) STAGE_V(kt0 + kt + 1, cur ^ 1);   // full tile to land

    const char* KsC = (const char*)&Ks[0];
    const char* VtC = (const char*)&Vt[cur][0];

    // ---- S = Q.K^T : each kf read feeds BOTH row-groups -------------------
    f32x4 sc[2][4];
#pragma unroll
    for (int rg = 0; rg < 2; ++rg)
#pragma unroll
      for (int ct = 0; ct < 4; ++ct) sc[rg][ct] = (f32x4){0.f, 0.f, 0.f, 0.f};
    __builtin_amdgcn_s_setprio(1);
#pragma unroll
    for (int ct = 0; ct < 4; ++ct)
#pragma unroll
      for (int ks = 0; ks < 8; ++ks) {
        f16x8 kf = *(const f16x8*)(KsC + ((ct * 16 + lr) << 9)
                                       + (((ks * 4 + lg) ^ sw) << 4));
        sc[0][ct] = __builtin_amdgcn_mfma_f32_16x16x32_f16(qf[0][ks], kf, sc[0][ct], 0, 0, 0);
        sc[1][ct] = __builtin_amdgcn_mfma_f32_16x16x32_f16(qf[1][ks], kf, sc[1][ct], 0, 0, 0);
      }
    __builtin_amdgcn_s_setprio(0);

    // raw barrier: all waves' QK reads of Ks are consumed (lgkmcnt waited
    // before each MFMA use); safe to overwrite Ks with next tile's loads.
    __builtin_amdgcn_s_barrier();
    if (pre) STAGE_K(kt0 + kt + 1);            // lands during softmax+PV

    // ---- online softmax with defer-max (per row-group) --------------------
    float tmv[2][4];
    int need = 0;
#pragma unroll
    for (int rg = 0; rg < 2; ++rg)
#pragma unroll
      for (int j = 0; j < 4; ++j) {
        float tm = fmaxf(fmaxf(sc[rg][0][j], sc[rg][1][j]),
                         fmaxf(sc[rg][2][j], sc[rg][3][j]));
        tm = fmaxf(tm, __shfl_xor(tm, 1, 16));
        tm = fmaxf(tm, __shfl_xor(tm, 2, 16));
        tm = fmaxf(tm, __shfl_xor(tm, 4, 16));
        tm = fmaxf(tm, __shfl_xor(tm, 8, 16));
        tmv[rg][j] = tm;
        need |= (tm > mrun[rg][j] + 8.f) ? 1 : 0;
      }
    if (__any(need)) {
#pragma unroll
      for (int rg = 0; rg < 2; ++rg)
#pragma unroll
        for (int j = 0; j < 4; ++j) {
          float mnew = fmaxf(mrun[rg][j], tmv[rg][j]);
          float scl  = __expf(mrun[rg][j] - mnew);
          mrun[rg][j] = mnew;
          lrun[rg][j] *= scl;
#pragma unroll
          for (int dt = 0; dt < 16; ++dt) cacc[rg][dt][j] *= scl;
        }
    }
#pragma unroll
    for (int rg = 0; rg < 2; ++rg)
#pragma unroll
      for (int j = 0; j < 4; ++j) {
        const int row = rg * 16 + lg * 4 + j;
        float ps = 0.f;
#pragma unroll
        for (int ct = 0; ct < 4; ++ct) {
          float p = __expf(sc[rg][ct][j] - mrun[rg][j]);   // bounded by e^8
          sc[rg][ct][j] = p; ps += p;
          const int g = (ct * 2 + (lr >> 3)) ^ (row & 7);
          Ps[w][row * 64 + g * 8 + (lr & 7)] = (_Float16)p;
        }
        ps += __shfl_xor(ps, 1, 16);
        ps += __shfl_xor(ps, 2, 16);
        ps += __shfl_xor(ps, 4, 16);
        ps += __shfl_xor(ps, 8, 16);
        lrun[rg][j] += ps;
      }

    // ---- ctx += P.V : each va/vb pair feeds 4 MFMAs -----------------------
    f16x8 pa[2][2];
#pragma unroll
    for (int rg = 0; rg < 2; ++rg)
#pragma unroll
      for (int h = 0; h < 2; ++h)
        pa[rg][h] = *(const f16x8*)(&Ps[w][(rg * 16 + lr) * 64
                                          + (((h * 4 + lg) ^ sw) * 8)]);
    __builtin_amdgcn_s_setprio(1);
#pragma unroll
    for (int dt = 0; dt < 16; ++dt) {
      const char* vrow = VtC + ((dt * 16 + lr) << 7);
      f16x8 va = *(const f16x8*)(vrow + ((lg ^ sw) << 4));
      f16x8 vb = *(const f16x8*)(vrow + (((lg + 4) ^ sw) << 4));
      cacc[0][dt] = __builtin_amdgcn_mfma_f32_16x16x32_f16(pa[0][0], va, cacc[0][dt], 0, 0, 0);
      cacc[0][dt] = __builtin_amdgcn_mfma_f32_16x16x32_f16(pa[0][1], vb, cacc[0][dt], 0, 0, 0);
      cacc[1][dt] = __builtin_amdgcn_mfma_f32_16x16x32_f16(pa[1][0], va, cacc[1][dt], 0, 0, 0);
      cacc[1][dt] = __builtin_amdgcn_mfma_f32_16x16x32_f16(pa[1][1], vb, cacc[1][dt], 0, 0, 0);
    }
    __builtin_amdgcn_s_setprio(0);

    __syncthreads();   // single vmcnt drain: V (full tile old) + K (SM+PV old)
    cur ^= 1;
  }

  // ---- epilogue: NORMALIZED partial ctx (f16) + m/l (f32) -----------------
#pragma unroll
  for (int rg = 0; rg < 2; ++rg) {
    const size_t Rbase = (size_t)b * SEQ + q0 + w * 32 + rg * 16;
#pragma unroll
    for (int j = 0; j < 4; ++j) {
      size_t R = Rbase + lg * 4 + j;
      if (lr == 0) {
        Mp[(size_t)split * RROWS + R] = mrun[rg][j];
        Lp[(size_t)split * RROWS + R] = lrun[rg][j];
      }
      float inv = 1.0f / lrun[rg][j];
#pragma unroll
      for (int dt = 0; dt < 16; ++dt)
        Op[((size_t)split * RROWS + R) * DD + dt * 16 + lr] =
            (_Float16)(cacc[rg][dt][j] * inv);
    }
  }
}

// ---------------------------------------------------------------------------
// Combine nsplit NORMALIZED partials:
// ctx = sum_s w_s*Op_s, w_s = e^{m_s-m*} l_s / sum(e^{m_i-m*} l_i).
// ---------------------------------------------------------------------------
__global__ __launch_bounds__(256) void attn_combine_kernel(
    const _Float16* __restrict__ Op, const float* __restrict__ Mp,
    const float* __restrict__ Lp, _Float16* __restrict__ ctx, int nsplit)
{
  const int lane = threadIdx.x & 63;
  const int w    = threadIdx.x >> 6;
  const size_t R = (size_t)blockIdx.x * 4 + w;
  float ms = -1e30f;
  for (int s = 0; s < nsplit; ++s) ms = fmaxf(ms, Mp[(size_t)s * RROWS + R]);
  float wgt[4], ctot = 0.f;
  for (int s = 0; s < nsplit; ++s) {
    float c = __expf(Mp[(size_t)s * RROWS + R] - ms) * Lp[(size_t)s * RROWS + R];
    wgt[s] = c; ctot += c;
  }
  float inv = 1.0f / ctot;
  float acc[4] = {0.f, 0.f, 0.f, 0.f};
  for (int s = 0; s < nsplit; ++s) {
    f16x4 o = *(const f16x4*)&Op[((size_t)s * RROWS + R) * DD + lane * 4];
#pragma unroll
    for (int i = 0; i < 4; ++i) acc[i] += wgt[s] * (float)o[i];
  }
  f16x4 o;
#pragma unroll
  for (int i = 0; i < 4; ++i) o[i] = (_Float16)(acc[i] * inv);
  *(f16x4*)&ctx[R * DD + lane * 4] = o;
}

// ---------------------------------------------------------------------------
// LayerNorm over last dim (256). One wave per row, 4 rows per block.
// ---------------------------------------------------------------------------
__global__ __launch_bounds__(256) void ln_kernel(
    const float* __restrict__ H, const float* __restrict__ g,
    const float* __restrict__ b, float* __restrict__ out)
{
  const int lane = threadIdx.x & 63;
  const int w    = threadIdx.x >> 6;
  const int r    = blockIdx.x * 4 + w;
  const size_t rowoff = (size_t)r * DD;
  float4 h4 = *(const float4*)&H[rowoff + lane * 4];
  float s = h4.x + h4.y + h4.z + h4.w;
#pragma unroll
  for (int m = 1; m < 64; m <<= 1) s += __shfl_xor(s, m, 64);
  float mu = s * (1.0f / 256.0f);
  float dx = h4.x - mu, dy = h4.y - mu, dz = h4.z - mu, dw = h4.w - mu;
  float v = dx*dx + dy*dy + dz*dz + dw*dw;
#pragma unroll
  for (int m = 1; m < 64; m <<= 1) v += __shfl_xor(v, m, 64);
  float rs = rsqrtf(v * (1.0f / 256.0f) + 1e-5f);
  float4 g4 = *(const float4*)&g[lane * 4];
  float4 b4 = *(const float4*)&b[lane * 4];
  float4 o;
  o.x = dx * rs * g4.x + b4.x;
  o.y = dy * rs * g4.y + b4.y;
  o.z = dz * rs * g4.z + b4.z;
  o.w = dw * rs * g4.w + b4.w;
  *(float4*)&out[rowoff + lane * 4] = o;
}

// ---------------------------------------------------------------------------
extern "C" void kernel_launch(void* const* d_in, const int* in_sizes, int n_in,
                              void* d_out, int out_size, void* d_ws, size_t ws_size,
                              hipStream_t stream) {
  const float* x  = (const float*)d_in[0];
  const float* Wq = (const float*)d_in[1];
  const float* bq = (const float*)d_in[2];
  const float* Wk = (const float*)d_in[3];
  const float* bk = (const float*)d_in[4];
  const float* Wv = (const float*)d_in[5];
  const float* bv = (const float*)d_in[6];
  const float* Wd = (const float*)d_in[7];
  const float* bd = (const float*)d_in[8];
  const float* g  = (const float*)d_in[9];
  const float* b  = (const float*)d_in[10];
  float* out = (float*)d_out;

  // nsplit=4 needs 57 MB of ws; fall back to 2 (41 MB, half-grid) if tight.
  const int nsplit = (ws_size >= (58ull << 20)) ? 4 : 2;

  char* W = (char*)d_ws;
  _Float16* Qh   = (_Float16*)(W + (0ull  << 20));   //  8 MB; later ctx
  _Float16* Kh   = (_Float16*)(W + (8ull  << 20));   //  8 MB, swizzled rows
  _Float16* VtG  = (_Float16*)(W + (16ull << 20));   //  8 MB, tiled+swizzled
  _Float16* Op   = (_Float16*)(W + (24ull << 20));   //  8*nsplit MB
  _Float16* xh   = (_Float16*)(W + (24ull << 20));   //  8 MB, overlays Op
                                                     //  (dead before attn)
  float*    Hf   = (float*)(W + (24ull << 20));      // 16 MB, overlays Op
                                                     //  (dead after combine)
  size_t tail = (24ull << 20) + (size_t)nsplit * (8ull << 20);
  float*    Mp   = (float*)(W + tail);
  float*    Lp   = Mp + (size_t)nsplit * RROWS;
  _Float16* Wh   = (_Float16*)(Lp + (size_t)nsplit * RROWS);   // 512 KB
  _Float16* ctxh = Qh;

  cast_x_kernel<<<2048, 256, 0, stream>>>(x, xh);
  cast_w_kernel<<<dim3(32, 4), 256, 0, stream>>>(Wq, Wk, Wv, Wd, Wh);

  dim3 gg(RROWS / 64, DD / 128);   // (256, 2)
  gemm16_kernel<1><<<gg, 256, 0, stream>>>(xh, Wh,             bq, nullptr, Qh);
  gemm16_kernel<3><<<gg, 256, 0, stream>>>(xh, Wh + 65536,     bk, nullptr, Kh);
  gemm16_kernel<2><<<gg, 256, 0, stream>>>(xh, Wh + 2 * 65536, bv, nullptr, VtG);

  // grid: 8 q-tiles x nsplit x 8 batches (= 256 blocks at nsplit=4)
  attn_partial_kernel<<<dim3((SEQ / QBLK) * nsplit * NB), 512, 0, stream>>>(
      Qh, Kh, VtG, Op, Mp, Lp, nsplit);
  attn_combine_kernel<<<RROWS / 4, 256, 0, stream>>>(Op, Mp, Lp, ctxh, nsplit);

  gemm16_kernel<0><<<gg, 256, 0, stream>>>(ctxh, Wh + 3 * 65536, bd, x, Hf);

  ln_kernel<<<RROWS / 4, 256, 0, stream>>>(Hf, g, b, out);
}

// Round 17
// 118.178 us; speedup vs baseline: 1.2844x; 1.2844x over previous
//
#include <hip/hip_runtime.h>
#include <hip/hip_bf16.h>
#include <hip/hip_fp16.h>
#include <cstdint>

// B=8, S=2048, D=256 fused attention block, fp32 in/out.
// Round 17: swapped-QK^T 32x32x16 attention (m214-style), 32 q-rows/wave,
// fits the 256-VGPR structural cap (8-wave block): P lane-local -> no Ps LDS,
// no 16-lane shfl softmax; P->A-operand via v_cvt_pkrtz + v_permlane32_swap.
// K pre-swizzle upgraded to ^(r&31). Geometry as round 16 (QBLK=256, KVBLK=64,
// K single-buffer + raw mid-tile barrier, V double-buffer, nsplit=4).

#define RROWS 16384
#define DD 256
#define SEQ 2048
#define NB 8
#define QBLK 256
#define KVBLK 64
#define NTILES (SEQ / KVBLK)

typedef _Float16 f16x8 __attribute__((ext_vector_type(8)));
typedef _Float16 f16x4 __attribute__((ext_vector_type(4)));
typedef _Float16 f16x2 __attribute__((ext_vector_type(2)));
typedef float f32x4 __attribute__((ext_vector_type(4)));
typedef float f32x16 __attribute__((ext_vector_type(16)));

// ---------------------------------------------------------------------------
// casts
// ---------------------------------------------------------------------------
__global__ __launch_bounds__(256) void cast_x_kernel(
    const float* __restrict__ src, _Float16* __restrict__ dst)
{
  const size_t i = ((size_t)blockIdx.x * 256 + threadIdx.x) * 8;
  float4 a = *(const float4*)&src[i];
  float4 b = *(const float4*)&src[i + 4];
  f16x8 h = { (_Float16)a.x, (_Float16)a.y, (_Float16)a.z, (_Float16)a.w,
              (_Float16)b.x, (_Float16)b.y, (_Float16)b.z, (_Float16)b.w };
  *(f16x8*)&dst[i] = h;
}

__global__ __launch_bounds__(256) void cast_w_kernel(
    const float* __restrict__ w0, const float* __restrict__ w1,
    const float* __restrict__ w2, const float* __restrict__ w3,
    _Float16* __restrict__ dst)
{
  const float* srcs[4] = {w0, w1, w2, w3};
  const float* src = srcs[blockIdx.y];
  _Float16* d = dst + (size_t)blockIdx.y * 65536;
  const size_t i = ((size_t)blockIdx.x * 256 + threadIdx.x) * 8;
  float4 a = *(const float4*)&src[i];
  float4 b = *(const float4*)&src[i + 4];
  f16x8 h = { (_Float16)a.x, (_Float16)a.y, (_Float16)a.z, (_Float16)a.w,
              (_Float16)b.x, (_Float16)b.y, (_Float16)b.z, (_Float16)b.w };
  *(f16x8*)&d[i] = h;
}

// ---------------------------------------------------------------------------
// fp16 MFMA GEMM: 64x128 tile, K=256.
// MODE 0: f32 out + res.          MODE 1: f16 row-major (Q).
// MODE 2: f16 TILED [b][s/64][256 d][64 s], granule swizzle ^(d&7) (V).
// MODE 3: f16 row-major, granule swizzle ^(r&31) (K):
//         elem(r,c) -> r*256 + (((c>>3) ^ (r&31))<<3) + (c&7).
// ---------------------------------------------------------------------------
template <int MODE>
__global__ __launch_bounds__(256) void gemm16_kernel(
    const _Float16* __restrict__ X, const _Float16* __restrict__ W,
    const float* __restrict__ bias, const float* __restrict__ res,
    void* __restrict__ outv)
{
  __shared__ _Float16 smem[128 * 264];
  const int t     = threadIdx.x;
  const int lane  = t & 63;
  const int w     = t >> 6;
  const int rows0 = blockIdx.x * 64;
  const int col0  = blockIdx.y * 128;
  const int lr = lane & 15;
  const int lg = lane >> 4;

#pragma unroll
  for (int i = 0; i < 16; ++i) {
    int ch = i * 256 + t;
    int er = ch >> 5, kc = (ch & 31) * 8;
    *(f16x8*)&smem[er * 264 + kc] = *(const f16x8*)&W[(size_t)(col0 + er) * DD + kc];
  }

  f16x8 qf[8];
  {
    const _Float16* xrow = X + (size_t)(rows0 + w * 16 + lr) * DD;
#pragma unroll
    for (int ks = 0; ks < 8; ++ks)
      qf[ks] = *(const f16x8*)(xrow + ks * 32 + lg * 8);
  }
  __syncthreads();

  f32x4 acc[8];
#pragma unroll
  for (int i = 0; i < 8; ++i) acc[i] = (f32x4){0.f, 0.f, 0.f, 0.f};

#pragma unroll
  for (int ct = 0; ct < 8; ++ct)
#pragma unroll
    for (int ks = 0; ks < 8; ++ks) {
      f16x8 wf = *(const f16x8*)&smem[(ct * 16 + lr) * 264 + ks * 32 + lg * 8];
      acc[ct] = __builtin_amdgcn_mfma_f32_16x16x32_f16(qf[ks], wf, acc[ct], 0, 0, 0);
    }

  float bf[8];
#pragma unroll
  for (int ct = 0; ct < 8; ++ct) bf[ct] = bias[col0 + ct * 16 + lr];

  if constexpr (MODE == 0) {
    float* out = (float*)outv;
#pragma unroll
    for (int ct = 0; ct < 8; ++ct)
#pragma unroll
      for (int j = 0; j < 4; ++j) {
        int r = rows0 + w * 16 + lg * 4 + j;
        int c = col0 + ct * 16 + lr;
        out[(size_t)r * DD + c] = acc[ct][j] + bf[ct] + res[(size_t)r * DD + c];
      }
  } else if constexpr (MODE == 1) {
    _Float16* out = (_Float16*)outv;
#pragma unroll
    for (int ct = 0; ct < 8; ++ct)
#pragma unroll
      for (int j = 0; j < 4; ++j) {
        int r = rows0 + w * 16 + lg * 4 + j;
        out[(size_t)r * DD + col0 + ct * 16 + lr] = (_Float16)(acc[ct][j] + bf[ct]);
      }
  } else if constexpr (MODE == 3) {   // K: row-major + 5-bit granule swizzle
    _Float16* out = (_Float16*)outv;
#pragma unroll
    for (int ct = 0; ct < 8; ++ct)
#pragma unroll
      for (int j = 0; j < 4; ++j) {
        int r = rows0 + w * 16 + lg * 4 + j;
        int c = col0 + ct * 16 + lr;
        out[(size_t)r * DD + (((c >> 3) ^ (r & 31)) << 3) + (c & 7)] =
            (_Float16)(acc[ct][j] + bf[ct]);
      }
  } else {  // MODE 2: tiled V^T [b][s/64][256 d][64 s] + granule swizzle
    __syncthreads();
    _Float16* T = smem;   // reuse: [128 e][72 s-pitch]
#pragma unroll
    for (int ct = 0; ct < 8; ++ct)
#pragma unroll
      for (int j = 0; j < 4; ++j)
        T[(ct * 16 + lr) * 72 + (w * 16 + lg * 4 + j)] = (_Float16)(acc[ct][j] + bf[ct]);
    __syncthreads();
    _Float16* out = (_Float16*)outv;
    const int bIdx = rows0 >> 11;
    const int tIdx = (rows0 & (SEQ - 1)) >> 6;
    _Float16* base = out + (((size_t)bIdx * NTILES + tIdx) * DD + col0) * KVBLK;
#pragma unroll
    for (int p = 0; p < 4; ++p) {
      int ch = p * 256 + t;
      int e = ch >> 3, sc = (ch & 7) * 8;
      int g = (sc >> 3) ^ (e & 7);
      *(f16x8*)&base[(size_t)e * KVBLK + (g << 3)] = *(const f16x8*)&T[e * 72 + sc];
    }
  }
}

// ---------------------------------------------------------------------------
// Swapped-QK^T 32x32x16 flash attention. 512 thr (8 waves), wave owns 32
// q-rows (QBLK=256). KVBLK=64 = 2 S^T tiles of 32. Per lane: q = lane&31,
// k-half hi = lane>>5. S^T = mfma(K,Q) -> lane holds 32 P values of ONE
// q-row; softmax in-lane + 1 shfl_xor(32). P->PV A-operand via cvt_pkrtz +
// v_permlane32_swap (16+8 ops). PV = mfma(P,V). No Ps LDS.
// K single-buffered (raw mid-tile barrier), V double-buffered, global
// layouts pre-swizzled (K ^r&31, V ^d&7). One vmcnt drain per tile.
// ---------------------------------------------------------------------------
__global__ __launch_bounds__(512) void attn_partial_kernel(
    const _Float16* __restrict__ Q, const _Float16* __restrict__ K,
    const _Float16* __restrict__ VT, _Float16* __restrict__ Op,
    float* __restrict__ Mp, float* __restrict__ Lp, int nsplit)
{
  __shared__ _Float16 Ks[KVBLK * DD];      // 32 KB single
  __shared__ _Float16 Vt[2][DD * KVBLK];   // 2 x 32 KB
  __shared__ float    Lw[8][32];           // 1 KB per-wave broadcast

  const int t     = threadIdx.x;
  const int lane  = t & 63;
  const int w     = t >> 6;
  const int lid   = blockIdx.x;
  const int b     = lid & 7;
  const int inner = lid >> 3;
  const int lsn   = (nsplit == 4) ? 2 : 1;
  const int split = inner & (nsplit - 1);
  const int q0    = (inner >> lsn) * QBLK;
  const int ntsp  = NTILES / nsplit;
  const int kt0   = split * ntsp;
  const int ql    = lane & 31;             // q-col (and kv row index)
  const int hi    = lane >> 5;             // k-half

  // Q fragments (B-operand): 16 k-steps x 8 halfs (64 VGPR)
  f16x8 qf[16];
  {
    const _Float16* qrow = Q + ((size_t)b * SEQ + q0 + w * 32 + ql) * DD;
#pragma unroll
    for (int ks = 0; ks < 16; ++ks)
      qf[ks] = *(const f16x8*)(qrow + ks * 16 + hi * 8);
  }

  const char* Kb = (const char*)(K + (size_t)b * SEQ * DD);
  const char* Vb = (const char*)(VT + (size_t)b * NTILES * (DD * KVBLK));

  auto STAGE_K = [&](int ktAbs) {
    const char* kg = Kb + (size_t)ktAbs * (KVBLK * DD) * 2;
    char* kl = (char*)&Ks[0];
#pragma unroll
    for (int i = 0; i < 4; ++i) {
      int off = i * 8192 + t * 16;
      __builtin_amdgcn_global_load_lds((const void*)(kg + off), (void*)(kl + off),
                                       16, 0, 0);
    }
  };
  auto STAGE_V = [&](int ktAbs, int buf) {
    const char* vg = Vb + (size_t)ktAbs * (DD * KVBLK) * 2;
    char* vl = (char*)&Vt[buf][0];
#pragma unroll
    for (int i = 0; i < 4; ++i) {
      int off = i * 8192 + t * 16;
      __builtin_amdgcn_global_load_lds((const void*)(vg + off), (void*)(vl + off),
                                       16, 0, 0);
    }
  };

  f32x16 cacc[8];
#pragma unroll
  for (int i = 0; i < 8; ++i)
#pragma unroll
    for (int r = 0; r < 16; ++r) cacc[i][r] = 0.f;
  float mrun = -1e30f, lrun = 0.f;

  STAGE_V(kt0, 0);
  STAGE_K(kt0);
  __syncthreads();

  int cur = 0;
  for (int kt = 0; kt < ntsp; ++kt) {
    const bool pre = (kt + 1 < ntsp);
    if (pre) STAGE_V(kt0 + kt + 1, cur ^ 1);

    const char* KsC = (const char*)&Ks[0];
    const char* VtC = (const char*)&Vt[cur][0];

    // ---- S^T = K.Q : 2 tiles x 16 k-steps, A=K frag, B=Q resident --------
    f32x16 sc[2];
#pragma unroll
    for (int kt2 = 0; kt2 < 2; ++kt2)
#pragma unroll
      for (int r = 0; r < 16; ++r) sc[kt2][r] = 0.f;
    __builtin_amdgcn_s_setprio(1);
#pragma unroll
    for (int kt2 = 0; kt2 < 2; ++kt2)
#pragma unroll
      for (int ks = 0; ks < 16; ++ks) {
        f16x8 kf = *(const f16x8*)(KsC + ((kt2 * 32 + ql) << 9)
                                       + (((ks * 2 + hi) ^ ql) << 4));
        sc[kt2] = __builtin_amdgcn_mfma_f32_32x32x16_f16(kf, qf[ks], sc[kt2], 0, 0, 0);
      }
    __builtin_amdgcn_s_setprio(0);

    // raw barrier: all waves' K reads returned (lgkm waited before MFMA use)
    __builtin_amdgcn_s_barrier();
    if (pre) STAGE_K(kt0 + kt + 1);      // lands during softmax + PV

    // ---- softmax: lane owns full row q (32 own + 32 partner k-vals) -------
    float tm = sc[0][0];
#pragma unroll
    for (int r = 1; r < 16; ++r) tm = fmaxf(tm, sc[0][r]);
#pragma unroll
    for (int r = 0; r < 16; ++r) tm = fmaxf(tm, sc[1][r]);
    tm = fmaxf(tm, __shfl_xor(tm, 32));
    if (__any(tm > mrun + 8.f)) {        // rare defer-max rescale
      float mnew = fmaxf(mrun, tm);
      float scl  = __expf(mrun - mnew);
      if (lane < 32) Lw[w][lane] = scl;
      float sv[16];
#pragma unroll
      for (int r = 0; r < 16; ++r)
        sv[r] = Lw[w][(r & 3) + 8 * (r >> 2) + 4 * hi];
#pragma unroll
      for (int dt = 0; dt < 8; ++dt)
#pragma unroll
        for (int r = 0; r < 16; ++r) cacc[dt][r] *= sv[r];
      lrun *= scl;
      mrun = mnew;
    }
    float ps = 0.f;
#pragma unroll
    for (int kt2 = 0; kt2 < 2; ++kt2)
#pragma unroll
      for (int r = 0; r < 16; ++r) {
        float p = __expf(sc[kt2][r] - mrun);   // bounded by e^8
        sc[kt2][r] = p;
        ps += p;
      }
    ps += __shfl_xor(ps, 32);
    lrun += ps;

    // ---- pack P -> PV A-fragments: 16 cvt_pkrtz + 8 permlane32_swap -------
    f16x8 pa[4];
#pragma unroll
    for (int s = 0; s < 4; ++s) {
      const int tile = s >> 1, rb = (s & 1) * 8;
      unsigned x1 = __builtin_bit_cast(unsigned,
          __builtin_amdgcn_cvt_pkrtz(sc[tile][rb + 0], sc[tile][rb + 1]));
      unsigned y1 = __builtin_bit_cast(unsigned,
          __builtin_amdgcn_cvt_pkrtz(sc[tile][rb + 4], sc[tile][rb + 5]));
      unsigned x2 = __builtin_bit_cast(unsigned,
          __builtin_amdgcn_cvt_pkrtz(sc[tile][rb + 2], sc[tile][rb + 3]));
      unsigned y2 = __builtin_bit_cast(unsigned,
          __builtin_amdgcn_cvt_pkrtz(sc[tile][rb + 6], sc[tile][rb + 7]));
      asm volatile("v_permlane32_swap_b32 %0, %1" : "+v"(x1), "+v"(y1));
      asm volatile("v_permlane32_swap_b32 %0, %1" : "+v"(x2), "+v"(y2));
      union { unsigned u[4]; f16x8 v; } pu;
      pu.u[0] = x1; pu.u[1] = x2; pu.u[2] = y1; pu.u[3] = y2;
      pa[s] = pu.v;
    }

    // ---- O += P.V : 8 d-tiles x 4 k-steps, A=pa, B=V frag -----------------
    __builtin_amdgcn_s_setprio(1);
#pragma unroll
    for (int dt = 0; dt < 8; ++dt)
#pragma unroll
      for (int st = 0; st < 4; ++st) {
        f16x8 vf = *(const f16x8*)(VtC + ((dt * 32 + ql) << 7)
                                       + (((st * 2 + hi) ^ (ql & 7)) << 4));
        cacc[dt] = __builtin_amdgcn_mfma_f32_32x32x16_f16(pa[st], vf, cacc[dt], 0, 0, 0);
      }
    __builtin_amdgcn_s_setprio(0);

    __syncthreads();   // drains vmcnt: K(t+1) + V(t+1) landed
    cur ^= 1;
  }

  // ---- epilogue: NORMALIZED partial ctx (f16) + m/l -----------------------
  if (lane < 32) {
    const size_t R = (size_t)b * SEQ + q0 + w * 32 + lane;
    Mp[(size_t)split * RROWS + R] = mrun;
    Lp[(size_t)split * RROWS + R] = lrun;
    Lw[w][lane] = lrun;
  }
  float inv[16];
#pragma unroll
  for (int r = 0; r < 16; ++r)
    inv[r] = 1.0f / Lw[w][(r & 3) + 8 * (r >> 2) + 4 * hi];
#pragma unroll
  for (int r = 0; r < 16; ++r) {
    const int q = (r & 3) + 8 * (r >> 2) + 4 * hi;
    const size_t R = (size_t)b * SEQ + q0 + w * 32 + q;
#pragma unroll
    for (int dt = 0; dt < 8; ++dt)
      Op[((size_t)split * RROWS + R) * DD + dt * 32 + ql] =
          (_Float16)(cacc[dt][r] * inv[r]);
  }
}

// ---------------------------------------------------------------------------
// Combine nsplit NORMALIZED partials.
// ---------------------------------------------------------------------------
__global__ __launch_bounds__(256) void attn_combine_kernel(
    const _Float16* __restrict__ Op, const float* __restrict__ Mp,
    const float* __restrict__ Lp, _Float16* __restrict__ ctx, int nsplit)
{
  const int lane = threadIdx.x & 63;
  const int w    = threadIdx.x >> 6;
  const size_t R = (size_t)blockIdx.x * 4 + w;
  float ms = -1e30f;
  for (int s = 0; s < nsplit; ++s) ms = fmaxf(ms, Mp[(size_t)s * RROWS + R]);
  float wgt[4], ctot = 0.f;
  for (int s = 0; s < nsplit; ++s) {
    float c = __expf(Mp[(size_t)s * RROWS + R] - ms) * Lp[(size_t)s * RROWS + R];
    wgt[s] = c; ctot += c;
  }
  float inv = 1.0f / ctot;
  float acc[4] = {0.f, 0.f, 0.f, 0.f};
  for (int s = 0; s < nsplit; ++s) {
    f16x4 o = *(const f16x4*)&Op[((size_t)s * RROWS + R) * DD + lane * 4];
#pragma unroll
    for (int i = 0; i < 4; ++i) acc[i] += wgt[s] * (float)o[i];
  }
  f16x4 o;
#pragma unroll
  for (int i = 0; i < 4; ++i) o[i] = (_Float16)(acc[i] * inv);
  *(f16x4*)&ctx[R * DD + lane * 4] = o;
}

// ---------------------------------------------------------------------------
// LayerNorm over last dim (256). One wave per row, 4 rows per block.
// ---------------------------------------------------------------------------
__global__ __launch_bounds__(256) void ln_kernel(
    const float* __restrict__ H, const float* __restrict__ g,
    const float* __restrict__ b, float* __restrict__ out)
{
  const int lane = threadIdx.x & 63;
  const int w    = threadIdx.x >> 6;
  const int r    = blockIdx.x * 4 + w;
  const size_t rowoff = (size_t)r * DD;
  float4 h4 = *(const float4*)&H[rowoff + lane * 4];
  float s = h4.x + h4.y + h4.z + h4.w;
#pragma unroll
  for (int m = 1; m < 64; m <<= 1) s += __shfl_xor(s, m, 64);
  float mu = s * (1.0f / 256.0f);
  float dx = h4.x - mu, dy = h4.y - mu, dz = h4.z - mu, dw = h4.w - mu;
  float v = dx*dx + dy*dy + dz*dz + dw*dw;
#pragma unroll
  for (int m = 1; m < 64; m <<= 1) v += __shfl_xor(v, m, 64);
  float rs = rsqrtf(v * (1.0f / 256.0f) + 1e-5f);
  float4 g4 = *(const float4*)&g[lane * 4];
  float4 b4 = *(const float4*)&b[lane * 4];
  float4 o;
  o.x = dx * rs * g4.x + b4.x;
  o.y = dy * rs * g4.y + b4.y;
  o.z = dz * rs * g4.z + b4.z;
  o.w = dw * rs * g4.w + b4.w;
  *(float4*)&out[rowoff + lane * 4] = o;
}

// ---------------------------------------------------------------------------
extern "C" void kernel_launch(void* const* d_in, const int* in_sizes, int n_in,
                              void* d_out, int out_size, void* d_ws, size_t ws_size,
                              hipStream_t stream) {
  const float* x  = (const float*)d_in[0];
  const float* Wq = (const float*)d_in[1];
  const float* bq = (const float*)d_in[2];
  const float* Wk = (const float*)d_in[3];
  const float* bk = (const float*)d_in[4];
  const float* Wv = (const float*)d_in[5];
  const float* bv = (const float*)d_in[6];
  const float* Wd = (const float*)d_in[7];
  const float* bd = (const float*)d_in[8];
  const float* g  = (const float*)d_in[9];
  const float* b  = (const float*)d_in[10];
  float* out = (float*)d_out;

  const int nsplit = (ws_size >= (58ull << 20)) ? 4 : 2;

  char* W = (char*)d_ws;
  _Float16* Qh   = (_Float16*)(W + (0ull  << 20));   //  8 MB; later ctx
  _Float16* Kh   = (_Float16*)(W + (8ull  << 20));   //  8 MB, swizzled ^r&31
  _Float16* VtG  = (_Float16*)(W + (16ull << 20));   //  8 MB, tiled+swizzled
  _Float16* Op   = (_Float16*)(W + (24ull << 20));   //  8*nsplit MB
  _Float16* xh   = (_Float16*)(W + (24ull << 20));   //  8 MB, overlays Op
  float*    Hf   = (float*)(W + (24ull << 20));      // 16 MB, overlays Op
  size_t tail = (24ull << 20) + (size_t)nsplit * (8ull << 20);
  float*    Mp   = (float*)(W + tail);
  float*    Lp   = Mp + (size_t)nsplit * RROWS;
  _Float16* Wh   = (_Float16*)(Lp + (size_t)nsplit * RROWS);   // 512 KB
  _Float16* ctxh = Qh;

  cast_x_kernel<<<2048, 256, 0, stream>>>(x, xh);
  cast_w_kernel<<<dim3(32, 4), 256, 0, stream>>>(Wq, Wk, Wv, Wd, Wh);

  dim3 gg(RROWS / 64, DD / 128);   // (256, 2)
  gemm16_kernel<1><<<gg, 256, 0, stream>>>(xh, Wh,             bq, nullptr, Qh);
  gemm16_kernel<3><<<gg, 256, 0, stream>>>(xh, Wh + 65536,     bk, nullptr, Kh);
  gemm16_kernel<2><<<gg, 256, 0, stream>>>(xh, Wh + 2 * 65536, bv, nullptr, VtG);

  // grid: 8 q-tiles x nsplit x 8 batches (= 256 blocks at nsplit=4)
  attn_partial_kernel<<<dim3((SEQ / QBLK) * nsplit * NB), 512, 0, stream>>>(
      Qh, Kh, VtG, Op, Mp, Lp, nsplit);
  attn_combine_kernel<<<RROWS / 4, 256, 0, stream>>>(Op, Mp, Lp, ctxh, nsplit);

  gemm16_kernel<0><<<gg, 256, 0, stream>>>(ctxh, Wh + 3 * 65536, bd, x, Hf);

  ln_kernel<<<RROWS / 4, 256, 0, stream>>>(Hf, g, b, out);
}

// Round 19
// 110.710 us; speedup vs baseline: 1.3711x; 1.0675x over previous
//
#include <hip/hip_runtime.h>
#include <hip/hip_bf16.h>
#include <hip/hip_fp16.h>
#include <cstdint>

// B=8, S=2048, D=256 fused attention block, fp32 in/out.
// Round 19 (= round 18 resubmit; infra ate the bench):
// (a) attn: sequential S^T 32-tiles (sc 16 regs live, not 32) -> fits
// 256-VGPR cap, no spill; rare tile-1 rescale also scales packed pa[0..1].
// (b) fused QKV projection kernel reading x fp32 directly (cast_x deleted).
// Rest as round 17 (swapped-QK^T 32x32, K single + raw barrier, V dbuf,
// pre-swizzled K ^r&31 / V ^d&7, nsplit=4, XCD batch locality).

#define RROWS 16384
#define DD 256
#define SEQ 2048
#define NB 8
#define QBLK 256
#define KVBLK 64
#define NTILES (SEQ / KVBLK)

typedef _Float16 f16x8 __attribute__((ext_vector_type(8)));
typedef _Float16 f16x4 __attribute__((ext_vector_type(4)));
typedef float f32x4 __attribute__((ext_vector_type(4)));
typedef float f32x16 __attribute__((ext_vector_type(16)));

// ---------------------------------------------------------------------------
// weight cast (q,k,v,d -> Wh[4][65536])
// ---------------------------------------------------------------------------
__global__ __launch_bounds__(256) void cast_w_kernel(
    const float* __restrict__ w0, const float* __restrict__ w1,
    const float* __restrict__ w2, const float* __restrict__ w3,
    _Float16* __restrict__ dst)
{
  const float* srcs[4] = {w0, w1, w2, w3};
  const float* src = srcs[blockIdx.y];
  _Float16* d = dst + (size_t)blockIdx.y * 65536;
  const size_t i = ((size_t)blockIdx.x * 256 + threadIdx.x) * 8;
  float4 a = *(const float4*)&src[i];
  float4 b = *(const float4*)&src[i + 4];
  f16x8 h = { (_Float16)a.x, (_Float16)a.y, (_Float16)a.z, (_Float16)a.w,
              (_Float16)b.x, (_Float16)b.y, (_Float16)b.z, (_Float16)b.w };
  *(f16x8*)&d[i] = h;
}

// ---------------------------------------------------------------------------
// Fused QKV projection: X fp32 -> {Qh (row-major), Kh (swizzled ^r&31),
// VtG (tiled [b][s/64][256 d][64 s], granule-swizzled ^d&7)}.
// 64x128 tile, K=256; A-fragments cast from f32 once, 3 W-stages sequential.
// ---------------------------------------------------------------------------
__global__ __launch_bounds__(256) void gemm_qkv_kernel(
    const float* __restrict__ X, const _Float16* __restrict__ Wh,
    const float* __restrict__ bq, const float* __restrict__ bk,
    const float* __restrict__ bv,
    _Float16* __restrict__ Qh, _Float16* __restrict__ Kh,
    _Float16* __restrict__ VtG)
{
  __shared__ _Float16 smem[128 * 264];
  const int t     = threadIdx.x;
  const int lane  = t & 63;
  const int w     = t >> 6;
  const int rows0 = blockIdx.x * 64;
  const int col0  = blockIdx.y * 128;
  const int lr = lane & 15;
  const int lg = lane >> 4;

  // A fragments from f32 x (cast fused)
  f16x8 qf[8];
  {
    const float* xrow = X + (size_t)(rows0 + w * 16 + lr) * DD;
#pragma unroll
    for (int ks = 0; ks < 8; ++ks) {
      float4 a = *(const float4*)&xrow[ks * 32 + lg * 8];
      float4 b = *(const float4*)&xrow[ks * 32 + lg * 8 + 4];
      qf[ks] = (f16x8){ (_Float16)a.x, (_Float16)a.y, (_Float16)a.z, (_Float16)a.w,
                        (_Float16)b.x, (_Float16)b.y, (_Float16)b.z, (_Float16)b.w };
    }
  }

  for (int o = 0; o < 3; ++o) {
    const _Float16* W = Wh + (size_t)o * 65536;
    __syncthreads();                 // previous stage's smem reads done
#pragma unroll
    for (int i = 0; i < 16; ++i) {
      int ch = i * 256 + t;
      int er = ch >> 5, kc = (ch & 31) * 8;
      *(f16x8*)&smem[er * 264 + kc] = *(const f16x8*)&W[(size_t)(col0 + er) * DD + kc];
    }
    __syncthreads();

    f32x4 acc[8];
#pragma unroll
    for (int i = 0; i < 8; ++i) acc[i] = (f32x4){0.f, 0.f, 0.f, 0.f};
#pragma unroll
    for (int ct = 0; ct < 8; ++ct)
#pragma unroll
      for (int ks = 0; ks < 8; ++ks) {
        f16x8 wf = *(const f16x8*)&smem[(ct * 16 + lr) * 264 + ks * 32 + lg * 8];
        acc[ct] = __builtin_amdgcn_mfma_f32_16x16x32_f16(qf[ks], wf, acc[ct], 0, 0, 0);
      }

    const float* bp = (o == 0) ? bq : (o == 1) ? bk : bv;
    float bf[8];
#pragma unroll
    for (int ct = 0; ct < 8; ++ct) bf[ct] = bp[col0 + ct * 16 + lr];

    if (o == 0) {                       // Q row-major
#pragma unroll
      for (int ct = 0; ct < 8; ++ct)
#pragma unroll
        for (int j = 0; j < 4; ++j) {
          int r = rows0 + w * 16 + lg * 4 + j;
          Qh[(size_t)r * DD + col0 + ct * 16 + lr] = (_Float16)(acc[ct][j] + bf[ct]);
        }
    } else if (o == 1) {                // K row-major + 5-bit granule swizzle
#pragma unroll
      for (int ct = 0; ct < 8; ++ct)
#pragma unroll
        for (int j = 0; j < 4; ++j) {
          int r = rows0 + w * 16 + lg * 4 + j;
          int c = col0 + ct * 16 + lr;
          Kh[(size_t)r * DD + (((c >> 3) ^ (r & 31)) << 3) + (c & 7)] =
              (_Float16)(acc[ct][j] + bf[ct]);
        }
    } else {                            // V tiled+swizzled via LDS transpose
      __syncthreads();
      _Float16* T = smem;   // [128 e][72 s]
#pragma unroll
      for (int ct = 0; ct < 8; ++ct)
#pragma unroll
        for (int j = 0; j < 4; ++j)
          T[(ct * 16 + lr) * 72 + (w * 16 + lg * 4 + j)] = (_Float16)(acc[ct][j] + bf[ct]);
      __syncthreads();
      const int bIdx = rows0 >> 11;
      const int tIdx = (rows0 & (SEQ - 1)) >> 6;
      _Float16* base = VtG + (((size_t)bIdx * NTILES + tIdx) * DD + col0) * KVBLK;
#pragma unroll
      for (int p = 0; p < 4; ++p) {
        int ch = p * 256 + t;
        int e = ch >> 3, sc = (ch & 7) * 8;
        int g = (sc >> 3) ^ (e & 7);
        *(f16x8*)&base[(size_t)e * KVBLK + (g << 3)] = *(const f16x8*)&T[e * 72 + sc];
      }
    }
  }
}

// ---------------------------------------------------------------------------
// Out-projection GEMM (f32 out + residual). 64x128 tile, K=256, f16 inputs.
// ---------------------------------------------------------------------------
__global__ __launch_bounds__(256) void gemm_out_kernel(
    const _Float16* __restrict__ X, const _Float16* __restrict__ W,
    const float* __restrict__ bias, const float* __restrict__ res,
    float* __restrict__ out)
{
  __shared__ _Float16 smem[128 * 264];
  const int t     = threadIdx.x;
  const int lane  = t & 63;
  const int w     = t >> 6;
  const int rows0 = blockIdx.x * 64;
  const int col0  = blockIdx.y * 128;
  const int lr = lane & 15;
  const int lg = lane >> 4;

#pragma unroll
  for (int i = 0; i < 16; ++i) {
    int ch = i * 256 + t;
    int er = ch >> 5, kc = (ch & 31) * 8;
    *(f16x8*)&smem[er * 264 + kc] = *(const f16x8*)&W[(size_t)(col0 + er) * DD + kc];
  }

  f16x8 qf[8];
  {
    const _Float16* xrow = X + (size_t)(rows0 + w * 16 + lr) * DD;
#pragma unroll
    for (int ks = 0; ks < 8; ++ks)
      qf[ks] = *(const f16x8*)(xrow + ks * 32 + lg * 8);
  }
  __syncthreads();

  f32x4 acc[8];
#pragma unroll
  for (int i = 0; i < 8; ++i) acc[i] = (f32x4){0.f, 0.f, 0.f, 0.f};
#pragma unroll
  for (int ct = 0; ct < 8; ++ct)
#pragma unroll
    for (int ks = 0; ks < 8; ++ks) {
      f16x8 wf = *(const f16x8*)&smem[(ct * 16 + lr) * 264 + ks * 32 + lg * 8];
      acc[ct] = __builtin_amdgcn_mfma_f32_16x16x32_f16(qf[ks], wf, acc[ct], 0, 0, 0);
    }

  float bf[8];
#pragma unroll
  for (int ct = 0; ct < 8; ++ct) bf[ct] = bias[col0 + ct * 16 + lr];
#pragma unroll
  for (int ct = 0; ct < 8; ++ct)
#pragma unroll
    for (int j = 0; j < 4; ++j) {
      int r = rows0 + w * 16 + lg * 4 + j;
      int c = col0 + ct * 16 + lr;
      out[(size_t)r * DD + c] = acc[ct][j] + bf[ct] + res[(size_t)r * DD + c];
    }
}

// ---------------------------------------------------------------------------
// Swapped-QK^T 32x32x16 flash attention, v8 (sequential S-tiles, no spill).
// 512 thr (8 waves), wave owns 32 q-rows. Per 64-kv tile:
//   QK(t0) -> softmax+pack pa[0..1] -> QK(t1) -> barrier+STAGE_K ->
//   softmax+pack pa[2..3] (rare rescale also scales pa[0..1]) -> PV(4 steps).
// K single-buffered, V double-buffered, pre-swizzled global layouts.
// ---------------------------------------------------------------------------
__global__ __launch_bounds__(512) void attn_partial_kernel(
    const _Float16* __restrict__ Q, const _Float16* __restrict__ K,
    const _Float16* __restrict__ VT, _Float16* __restrict__ Op,
    float* __restrict__ Mp, float* __restrict__ Lp, int nsplit)
{
  __shared__ _Float16 Ks[KVBLK * DD];      // 32 KB single
  __shared__ _Float16 Vt[2][DD * KVBLK];   // 2 x 32 KB
  __shared__ float    Lw[8][32];           // 1 KB per-wave broadcast

  const int t     = threadIdx.x;
  const int lane  = t & 63;
  const int w     = t >> 6;
  const int lid   = blockIdx.x;
  const int b     = lid & 7;
  const int inner = lid >> 3;
  const int lsn   = (nsplit == 4) ? 2 : 1;
  const int split = inner & (nsplit - 1);
  const int q0    = (inner >> lsn) * QBLK;
  const int ntsp  = NTILES / nsplit;
  const int kt0   = split * ntsp;
  const int ql    = lane & 31;
  const int hi    = lane >> 5;

  // Q fragments (B-operand): 16 k-steps x 8 halfs (64 VGPR)
  f16x8 qf[16];
  {
    const _Float16* qrow = Q + ((size_t)b * SEQ + q0 + w * 32 + ql) * DD;
#pragma unroll
    for (int ks = 0; ks < 16; ++ks)
      qf[ks] = *(const f16x8*)(qrow + ks * 16 + hi * 8);
  }

  const char* Kb = (const char*)(K + (size_t)b * SEQ * DD);
  const char* Vb = (const char*)(VT + (size_t)b * NTILES * (DD * KVBLK));

  auto STAGE_K = [&](int ktAbs) {
    const char* kg = Kb + (size_t)ktAbs * (KVBLK * DD) * 2;
    char* kl = (char*)&Ks[0];
#pragma unroll
    for (int i = 0; i < 4; ++i) {
      int off = i * 8192 + t * 16;
      __builtin_amdgcn_global_load_lds((const void*)(kg + off), (void*)(kl + off),
                                       16, 0, 0);
    }
  };
  auto STAGE_V = [&](int ktAbs, int buf) {
    const char* vg = Vb + (size_t)ktAbs * (DD * KVBLK) * 2;
    char* vl = (char*)&Vt[buf][0];
#pragma unroll
    for (int i = 0; i < 4; ++i) {
      int off = i * 8192 + t * 16;
      __builtin_amdgcn_global_load_lds((const void*)(vg + off), (void*)(vl + off),
                                       16, 0, 0);
    }
  };

  f32x16 cacc[8];
#pragma unroll
  for (int i = 0; i < 8; ++i)
#pragma unroll
    for (int r = 0; r < 16; ++r) cacc[i][r] = 0.f;
  float mrun = -1e30f, lrun = 0.f;

  STAGE_V(kt0, 0);
  STAGE_K(kt0);
  __syncthreads();

  int cur = 0;
  for (int kt = 0; kt < ntsp; ++kt) {
    const bool pre = (kt + 1 < ntsp);
    if (pre) STAGE_V(kt0 + kt + 1, cur ^ 1);

    const char* KsC = (const char*)&Ks[0];
    const char* VtC = (const char*)&Vt[cur][0];
    f16x8 pa[4];

    // ================= S^T tile 0 =================
    f32x16 sc;
#pragma unroll
    for (int r = 0; r < 16; ++r) sc[r] = 0.f;
    __builtin_amdgcn_s_setprio(1);
#pragma unroll
    for (int ks = 0; ks < 16; ++ks) {
      f16x8 kf = *(const f16x8*)(KsC + (ql << 9) + (((ks * 2 + hi) ^ ql) << 4));
      sc = __builtin_amdgcn_mfma_f32_32x32x16_f16(kf, qf[ks], sc, 0, 0, 0);
    }
    __builtin_amdgcn_s_setprio(0);

    {
      float tm = sc[0];
#pragma unroll
      for (int r = 1; r < 16; ++r) tm = fmaxf(tm, sc[r]);
      tm = fmaxf(tm, __shfl_xor(tm, 32));
      if (__any(tm > mrun + 8.f)) {
        float mnew = fmaxf(mrun, tm);
        float scl  = __expf(mrun - mnew);
        if (lane < 32) Lw[w][lane] = scl;
        float sv[16];
#pragma unroll
        for (int r = 0; r < 16; ++r)
          sv[r] = Lw[w][(r & 3) + 8 * (r >> 2) + 4 * hi];
#pragma unroll
        for (int dt = 0; dt < 8; ++dt)
#pragma unroll
          for (int r = 0; r < 16; ++r) cacc[dt][r] *= sv[r];
        lrun *= scl;
        mrun = mnew;
      }
      float ps = 0.f;
#pragma unroll
      for (int r = 0; r < 16; ++r) {
        float p = __expf(sc[r] - mrun);
        sc[r] = p; ps += p;
      }
      ps += __shfl_xor(ps, 32);
      lrun += ps;
      // pack -> pa[0], pa[1]
#pragma unroll
      for (int h = 0; h < 2; ++h) {
        const int rb = h * 8;
        unsigned x1 = __builtin_bit_cast(unsigned,
            __builtin_amdgcn_cvt_pkrtz(sc[rb + 0], sc[rb + 1]));
        unsigned y1 = __builtin_bit_cast(unsigned,
            __builtin_amdgcn_cvt_pkrtz(sc[rb + 4], sc[rb + 5]));
        unsigned x2 = __builtin_bit_cast(unsigned,
            __builtin_amdgcn_cvt_pkrtz(sc[rb + 2], sc[rb + 3]));
        unsigned y2 = __builtin_bit_cast(unsigned,
            __builtin_amdgcn_cvt_pkrtz(sc[rb + 6], sc[rb + 7]));
        asm volatile("v_permlane32_swap_b32 %0, %1" : "+v"(x1), "+v"(y1));
        asm volatile("v_permlane32_swap_b32 %0, %1" : "+v"(x2), "+v"(y2));
        union { unsigned u[4]; f16x8 v; } pu;
        pu.u[0] = x1; pu.u[1] = x2; pu.u[2] = y1; pu.u[3] = y2;
        pa[h] = pu.v;
      }
    }

    // ================= S^T tile 1 =================
#pragma unroll
    for (int r = 0; r < 16; ++r) sc[r] = 0.f;
    __builtin_amdgcn_s_setprio(1);
#pragma unroll
    for (int ks = 0; ks < 16; ++ks) {
      f16x8 kf = *(const f16x8*)(KsC + ((32 + ql) << 9) + (((ks * 2 + hi) ^ ql) << 4));
      sc = __builtin_amdgcn_mfma_f32_32x32x16_f16(kf, qf[ks], sc, 0, 0, 0);
    }
    __builtin_amdgcn_s_setprio(0);

    // all K reads of this tile consumed -> safe to restage Ks
    __builtin_amdgcn_s_barrier();
    if (pre) STAGE_K(kt0 + kt + 1);      // lands during softmax + PV

    {
      float tm = sc[0];
#pragma unroll
      for (int r = 1; r < 16; ++r) tm = fmaxf(tm, sc[r]);
      tm = fmaxf(tm, __shfl_xor(tm, 32));
      if (__any(tm > mrun + 8.f)) {      // rare: also rescale packed pa[0..1]
        float mnew = fmaxf(mrun, tm);
        float scl  = __expf(mrun - mnew);
        if (lane < 32) Lw[w][lane] = scl;
        float sv[16];
#pragma unroll
        for (int r = 0; r < 16; ++r)
          sv[r] = Lw[w][(r & 3) + 8 * (r >> 2) + 4 * hi];
#pragma unroll
        for (int dt = 0; dt < 8; ++dt)
#pragma unroll
          for (int r = 0; r < 16; ++r) cacc[dt][r] *= sv[r];
        lrun *= scl;
        mrun = mnew;
        _Float16 sh = (_Float16)scl;     // pa holds only q-row ql (lane pair)
#pragma unroll
        for (int e = 0; e < 8; ++e) { pa[0][e] *= sh; pa[1][e] *= sh; }
      }
      float ps = 0.f;
#pragma unroll
      for (int r = 0; r < 16; ++r) {
        float p = __expf(sc[r] - mrun);
        sc[r] = p; ps += p;
      }
      ps += __shfl_xor(ps, 32);
      lrun += ps;
#pragma unroll
      for (int h = 0; h < 2; ++h) {
        const int rb = h * 8;
        unsigned x1 = __builtin_bit_cast(unsigned,
            __builtin_amdgcn_cvt_pkrtz(sc[rb + 0], sc[rb + 1]));
        unsigned y1 = __builtin_bit_cast(unsigned,
            __builtin_amdgcn_cvt_pkrtz(sc[rb + 4], sc[rb + 5]));
        unsigned x2 = __builtin_bit_cast(unsigned,
            __builtin_amdgcn_cvt_pkrtz(sc[rb + 2], sc[rb + 3]));
        unsigned y2 = __builtin_bit_cast(unsigned,
            __builtin_amdgcn_cvt_pkrtz(sc[rb + 6], sc[rb + 7]));
        asm volatile("v_permlane32_swap_b32 %0, %1" : "+v"(x1), "+v"(y1));
        asm volatile("v_permlane32_swap_b32 %0, %1" : "+v"(x2), "+v"(y2));
        union { unsigned u[4]; f16x8 v; } pu;
        pu.u[0] = x1; pu.u[1] = x2; pu.u[2] = y1; pu.u[3] = y2;
        pa[2 + h] = pu.v;
      }
    }

    // ================= O += P.V =================
    __builtin_amdgcn_s_setprio(1);
#pragma unroll
    for (int dt = 0; dt < 8; ++dt)
#pragma unroll
      for (int st = 0; st < 4; ++st) {
        f16x8 vf = *(const f16x8*)(VtC + ((dt * 32 + ql) << 7)
                                       + (((st * 2 + hi) ^ (ql & 7)) << 4));
        cacc[dt] = __builtin_amdgcn_mfma_f32_32x32x16_f16(pa[st], vf, cacc[dt], 0, 0, 0);
      }
    __builtin_amdgcn_s_setprio(0);

    __syncthreads();   // drains vmcnt: K(t+1) + V(t+1) landed
    cur ^= 1;
  }

  // ---- epilogue: NORMALIZED partial ctx (f16) + m/l -----------------------
  if (lane < 32) {
    const size_t R = (size_t)b * SEQ + q0 + w * 32 + lane;
    Mp[(size_t)split * RROWS + R] = mrun;
    Lp[(size_t)split * RROWS + R] = lrun;
    Lw[w][lane] = lrun;
  }
  float inv[16];
#pragma unroll
  for (int r = 0; r < 16; ++r)
    inv[r] = 1.0f / Lw[w][(r & 3) + 8 * (r >> 2) + 4 * hi];
#pragma unroll
  for (int r = 0; r < 16; ++r) {
    const int q = (r & 3) + 8 * (r >> 2) + 4 * hi;
    const size_t R = (size_t)b * SEQ + q0 + w * 32 + q;
#pragma unroll
    for (int dt = 0; dt < 8; ++dt)
      Op[((size_t)split * RROWS + R) * DD + dt * 32 + ql] =
          (_Float16)(cacc[dt][r] * inv[r]);
  }
}

// ---------------------------------------------------------------------------
// Combine nsplit NORMALIZED partials.
// ---------------------------------------------------------------------------
__global__ __launch_bounds__(256) void attn_combine_kernel(
    const _Float16* __restrict__ Op, const float* __restrict__ Mp,
    const float* __restrict__ Lp, _Float16* __restrict__ ctx, int nsplit)
{
  const int lane = threadIdx.x & 63;
  const int w    = threadIdx.x >> 6;
  const size_t R = (size_t)blockIdx.x * 4 + w;
  float ms = -1e30f;
  for (int s = 0; s < nsplit; ++s) ms = fmaxf(ms, Mp[(size_t)s * RROWS + R]);
  float wgt[4], ctot = 0.f;
  for (int s = 0; s < nsplit; ++s) {
    float c = __expf(Mp[(size_t)s * RROWS + R] - ms) * Lp[(size_t)s * RROWS + R];
    wgt[s] = c; ctot += c;
  }
  float inv = 1.0f / ctot;
  float acc[4] = {0.f, 0.f, 0.f, 0.f};
  for (int s = 0; s < nsplit; ++s) {
    f16x4 o = *(const f16x4*)&Op[((size_t)s * RROWS + R) * DD + lane * 4];
#pragma unroll
    for (int i = 0; i < 4; ++i) acc[i] += wgt[s] * (float)o[i];
  }
  f16x4 o;
#pragma unroll
  for (int i = 0; i < 4; ++i) o[i] = (_Float16)(acc[i] * inv);
  *(f16x4*)&ctx[R * DD + lane * 4] = o;
}

// ---------------------------------------------------------------------------
// LayerNorm over last dim (256). One wave per row, 4 rows per block.
// ---------------------------------------------------------------------------
__global__ __launch_bounds__(256) void ln_kernel(
    const float* __restrict__ H, const float* __restrict__ g,
    const float* __restrict__ b, float* __restrict__ out)
{
  const int lane = threadIdx.x & 63;
  const int w    = threadIdx.x >> 6;
  const int r    = blockIdx.x * 4 + w;
  const size_t rowoff = (size_t)r * DD;
  float4 h4 = *(const float4*)&H[rowoff + lane * 4];
  float s = h4.x + h4.y + h4.z + h4.w;
#pragma unroll
  for (int m = 1; m < 64; m <<= 1) s += __shfl_xor(s, m, 64);
  float mu = s * (1.0f / 256.0f);
  float dx = h4.x - mu, dy = h4.y - mu, dz = h4.z - mu, dw = h4.w - mu;
  float v = dx*dx + dy*dy + dz*dz + dw*dw;
#pragma unroll
  for (int m = 1; m < 64; m <<= 1) v += __shfl_xor(v, m, 64);
  float rs = rsqrtf(v * (1.0f / 256.0f) + 1e-5f);
  float4 g4 = *(const float4*)&g[lane * 4];
  float4 b4 = *(const float4*)&b[lane * 4];
  float4 o;
  o.x = dx * rs * g4.x + b4.x;
  o.y = dy * rs * g4.y + b4.y;
  o.z = dz * rs * g4.z + b4.z;
  o.w = dw * rs * g4.w + b4.w;
  *(float4*)&out[rowoff + lane * 4] = o;
}

// ---------------------------------------------------------------------------
extern "C" void kernel_launch(void* const* d_in, const int* in_sizes, int n_in,
                              void* d_out, int out_size, void* d_ws, size_t ws_size,
                              hipStream_t stream) {
  const float* x  = (const float*)d_in[0];
  const float* Wq = (const float*)d_in[1];
  const float* bq = (const float*)d_in[2];
  const float* Wk = (const float*)d_in[3];
  const float* bk = (const float*)d_in[4];
  const float* Wv = (const float*)d_in[5];
  const float* bv = (const float*)d_in[6];
  const float* Wd = (const float*)d_in[7];
  const float* bd = (const float*)d_in[8];
  const float* g  = (const float*)d_in[9];
  const float* b  = (const float*)d_in[10];
  float* out = (float*)d_out;

  const int nsplit = (ws_size >= (58ull << 20)) ? 4 : 2;

  char* W = (char*)d_ws;
  _Float16* Qh   = (_Float16*)(W + (0ull  << 20));   //  8 MB; later ctx
  _Float16* Kh   = (_Float16*)(W + (8ull  << 20));   //  8 MB, swizzled ^r&31
  _Float16* VtG  = (_Float16*)(W + (16ull << 20));   //  8 MB, tiled+swizzled
  _Float16* Op   = (_Float16*)(W + (24ull << 20));   //  8*nsplit MB
  float*    Hf   = (float*)(W + (24ull << 20));      // 16 MB, overlays Op
  size_t tail = (24ull << 20) + (size_t)nsplit * (8ull << 20);
  float*    Mp   = (float*)(W + tail);
  float*    Lp   = Mp + (size_t)nsplit * RROWS;
  _Float16* Wh   = (_Float16*)(Lp + (size_t)nsplit * RROWS);   // 512 KB
  _Float16* ctxh = Qh;

  cast_w_kernel<<<dim3(32, 4), 256, 0, stream>>>(Wq, Wk, Wv, Wd, Wh);

  dim3 gg(RROWS / 64, DD / 128);   // (256, 2)
  gemm_qkv_kernel<<<gg, 256, 0, stream>>>(x, Wh, bq, bk, bv, Qh, Kh, VtG);

  // grid: 8 q-tiles x nsplit x 8 batches (= 256 blocks at nsplit=4)
  attn_partial_kernel<<<dim3((SEQ / QBLK) * nsplit * NB), 512, 0, stream>>>(
      Qh, Kh, VtG, Op, Mp, Lp, nsplit);
  attn_combine_kernel<<<RROWS / 4, 256, 0, stream>>>(Op, Mp, Lp, ctxh, nsplit);

  gemm_out_kernel<<<gg, 256, 0, stream>>>(ctxh, Wh + 3 * 65536, bd, x, Hf);

  ln_kernel<<<RROWS / 4, 256, 0, stream>>>(Hf, g, b, out);
}

// Round 20
// 100.994 us; speedup vs baseline: 1.5030x; 1.0962x over previous
//
#include <hip/hip_runtime.h>
#include <hip/hip_bf16.h>
#include <hip/hip_fp16.h>
#include <cstdint>

// B=8, S=2048, D=256 fused attention block, fp32 in/out.
// Round 20: kill the residual spill (~9MB W / 5MB R at VGPR cap 128+128):
//   (a) PV split in halves -> only pa[0..1] live (-8 VGPR); tile-1 rescale
//       naturally covers half-0 contribution (no pa-rescale hack).
//   (b) rescale loop uses a scalar temp, not sv[16] (-16 VGPR).
// Arch demand ~108 <= 128 -> no scratch. Rest as round 19 (swapped-QK^T
// 32x32, fused QKV, K single + raw barrier, V dbuf, pre-swizzled layouts).

#define RROWS 16384
#define DD 256
#define SEQ 2048
#define NB 8
#define QBLK 256
#define KVBLK 64
#define NTILES (SEQ / KVBLK)

typedef _Float16 f16x8 __attribute__((ext_vector_type(8)));
typedef _Float16 f16x4 __attribute__((ext_vector_type(4)));
typedef float f32x4 __attribute__((ext_vector_type(4)));
typedef float f32x16 __attribute__((ext_vector_type(16)));

// ---------------------------------------------------------------------------
// weight cast (q,k,v,d -> Wh[4][65536])
// ---------------------------------------------------------------------------
__global__ __launch_bounds__(256) void cast_w_kernel(
    const float* __restrict__ w0, const float* __restrict__ w1,
    const float* __restrict__ w2, const float* __restrict__ w3,
    _Float16* __restrict__ dst)
{
  const float* srcs[4] = {w0, w1, w2, w3};
  const float* src = srcs[blockIdx.y];
  _Float16* d = dst + (size_t)blockIdx.y * 65536;
  const size_t i = ((size_t)blockIdx.x * 256 + threadIdx.x) * 8;
  float4 a = *(const float4*)&src[i];
  float4 b = *(const float4*)&src[i + 4];
  f16x8 h = { (_Float16)a.x, (_Float16)a.y, (_Float16)a.z, (_Float16)a.w,
              (_Float16)b.x, (_Float16)b.y, (_Float16)b.z, (_Float16)b.w };
  *(f16x8*)&d[i] = h;
}

// ---------------------------------------------------------------------------
// Fused QKV projection: X fp32 -> {Qh (row-major), Kh (swizzled ^r&31),
// VtG (tiled [b][s/64][256 d][64 s], granule-swizzled ^d&7)}.
// ---------------------------------------------------------------------------
__global__ __launch_bounds__(256) void gemm_qkv_kernel(
    const float* __restrict__ X, const _Float16* __restrict__ Wh,
    const float* __restrict__ bq, const float* __restrict__ bk,
    const float* __restrict__ bv,
    _Float16* __restrict__ Qh, _Float16* __restrict__ Kh,
    _Float16* __restrict__ VtG)
{
  __shared__ _Float16 smem[128 * 264];
  const int t     = threadIdx.x;
  const int lane  = t & 63;
  const int w     = t >> 6;
  const int rows0 = blockIdx.x * 64;
  const int col0  = blockIdx.y * 128;
  const int lr = lane & 15;
  const int lg = lane >> 4;

  f16x8 qf[8];
  {
    const float* xrow = X + (size_t)(rows0 + w * 16 + lr) * DD;
#pragma unroll
    for (int ks = 0; ks < 8; ++ks) {
      float4 a = *(const float4*)&xrow[ks * 32 + lg * 8];
      float4 b = *(const float4*)&xrow[ks * 32 + lg * 8 + 4];
      qf[ks] = (f16x8){ (_Float16)a.x, (_Float16)a.y, (_Float16)a.z, (_Float16)a.w,
                        (_Float16)b.x, (_Float16)b.y, (_Float16)b.z, (_Float16)b.w };
    }
  }

  for (int o = 0; o < 3; ++o) {
    const _Float16* W = Wh + (size_t)o * 65536;
    __syncthreads();
#pragma unroll
    for (int i = 0; i < 16; ++i) {
      int ch = i * 256 + t;
      int er = ch >> 5, kc = (ch & 31) * 8;
      *(f16x8*)&smem[er * 264 + kc] = *(const f16x8*)&W[(size_t)(col0 + er) * DD + kc];
    }
    __syncthreads();

    f32x4 acc[8];
#pragma unroll
    for (int i = 0; i < 8; ++i) acc[i] = (f32x4){0.f, 0.f, 0.f, 0.f};
#pragma unroll
    for (int ct = 0; ct < 8; ++ct)
#pragma unroll
      for (int ks = 0; ks < 8; ++ks) {
        f16x8 wf = *(const f16x8*)&smem[(ct * 16 + lr) * 264 + ks * 32 + lg * 8];
        acc[ct] = __builtin_amdgcn_mfma_f32_16x16x32_f16(qf[ks], wf, acc[ct], 0, 0, 0);
      }

    const float* bp = (o == 0) ? bq : (o == 1) ? bk : bv;
    float bf[8];
#pragma unroll
    for (int ct = 0; ct < 8; ++ct) bf[ct] = bp[col0 + ct * 16 + lr];

    if (o == 0) {
#pragma unroll
      for (int ct = 0; ct < 8; ++ct)
#pragma unroll
        for (int j = 0; j < 4; ++j) {
          int r = rows0 + w * 16 + lg * 4 + j;
          Qh[(size_t)r * DD + col0 + ct * 16 + lr] = (_Float16)(acc[ct][j] + bf[ct]);
        }
    } else if (o == 1) {
#pragma unroll
      for (int ct = 0; ct < 8; ++ct)
#pragma unroll
        for (int j = 0; j < 4; ++j) {
          int r = rows0 + w * 16 + lg * 4 + j;
          int c = col0 + ct * 16 + lr;
          Kh[(size_t)r * DD + (((c >> 3) ^ (r & 31)) << 3) + (c & 7)] =
              (_Float16)(acc[ct][j] + bf[ct]);
        }
    } else {
      __syncthreads();
      _Float16* T = smem;   // [128 e][72 s]
#pragma unroll
      for (int ct = 0; ct < 8; ++ct)
#pragma unroll
        for (int j = 0; j < 4; ++j)
          T[(ct * 16 + lr) * 72 + (w * 16 + lg * 4 + j)] = (_Float16)(acc[ct][j] + bf[ct]);
      __syncthreads();
      const int bIdx = rows0 >> 11;
      const int tIdx = (rows0 & (SEQ - 1)) >> 6;
      _Float16* base = VtG + (((size_t)bIdx * NTILES + tIdx) * DD + col0) * KVBLK;
#pragma unroll
      for (int p = 0; p < 4; ++p) {
        int ch = p * 256 + t;
        int e = ch >> 3, sc = (ch & 7) * 8;
        int g = (sc >> 3) ^ (e & 7);
        *(f16x8*)&base[(size_t)e * KVBLK + (g << 3)] = *(const f16x8*)&T[e * 72 + sc];
      }
    }
  }
}

// ---------------------------------------------------------------------------
// Out-projection GEMM (f32 out + residual). 64x128 tile, K=256, f16 inputs.
// ---------------------------------------------------------------------------
__global__ __launch_bounds__(256) void gemm_out_kernel(
    const _Float16* __restrict__ X, const _Float16* __restrict__ W,
    const float* __restrict__ bias, const float* __restrict__ res,
    float* __restrict__ out)
{
  __shared__ _Float16 smem[128 * 264];
  const int t     = threadIdx.x;
  const int lane  = t & 63;
  const int w     = t >> 6;
  const int rows0 = blockIdx.x * 64;
  const int col0  = blockIdx.y * 128;
  const int lr = lane & 15;
  const int lg = lane >> 4;

#pragma unroll
  for (int i = 0; i < 16; ++i) {
    int ch = i * 256 + t;
    int er = ch >> 5, kc = (ch & 31) * 8;
    *(f16x8*)&smem[er * 264 + kc] = *(const f16x8*)&W[(size_t)(col0 + er) * DD + kc];
  }

  f16x8 qf[8];
  {
    const _Float16* xrow = X + (size_t)(rows0 + w * 16 + lr) * DD;
#pragma unroll
    for (int ks = 0; ks < 8; ++ks)
      qf[ks] = *(const f16x8*)(xrow + ks * 32 + lg * 8);
  }
  __syncthreads();

  f32x4 acc[8];
#pragma unroll
  for (int i = 0; i < 8; ++i) acc[i] = (f32x4){0.f, 0.f, 0.f, 0.f};
#pragma unroll
  for (int ct = 0; ct < 8; ++ct)
#pragma unroll
    for (int ks = 0; ks < 8; ++ks) {
      f16x8 wf = *(const f16x8*)&smem[(ct * 16 + lr) * 264 + ks * 32 + lg * 8];
      acc[ct] = __builtin_amdgcn_mfma_f32_16x16x32_f16(qf[ks], wf, acc[ct], 0, 0, 0);
    }

  float bf[8];
#pragma unroll
  for (int ct = 0; ct < 8; ++ct) bf[ct] = bias[col0 + ct * 16 + lr];
#pragma unroll
  for (int ct = 0; ct < 8; ++ct)
#pragma unroll
    for (int j = 0; j < 4; ++j) {
      int r = rows0 + w * 16 + lg * 4 + j;
      int c = col0 + ct * 16 + lr;
      out[(size_t)r * DD + c] = acc[ct][j] + bf[ct] + res[(size_t)r * DD + c];
    }
}

// ---------------------------------------------------------------------------
// Swapped-QK^T 32x32x16 flash attention, v9 (half-PV interleave, no spill).
// 512 thr (8 waves), wave owns 32 q-rows. Per 64-kv tile:
//   QK(t0) -> SM0 -> pack pa01 -> PV(st0,1) -> QK(t1) -> barrier+STAGE_K ->
//   SM1 (rescale covers half-0 in cacc) -> pack pa01 -> PV(st2,3) -> drain.
// Only 2 pa fragments live; rescale uses a scalar temp. Arch VGPR ~108.
// ---------------------------------------------------------------------------
__global__ __launch_bounds__(512) void attn_partial_kernel(
    const _Float16* __restrict__ Q, const _Float16* __restrict__ K,
    const _Float16* __restrict__ VT, _Float16* __restrict__ Op,
    float* __restrict__ Mp, float* __restrict__ Lp, int nsplit)
{
  __shared__ _Float16 Ks[KVBLK * DD];      // 32 KB single
  __shared__ _Float16 Vt[2][DD * KVBLK];   // 2 x 32 KB
  __shared__ float    Lw[8][32];           // 1 KB per-wave broadcast

  const int t     = threadIdx.x;
  const int lane  = t & 63;
  const int w     = t >> 6;
  const int lid   = blockIdx.x;
  const int b     = lid & 7;
  const int inner = lid >> 3;
  const int lsn   = (nsplit == 4) ? 2 : 1;
  const int split = inner & (nsplit - 1);
  const int q0    = (inner >> lsn) * QBLK;
  const int ntsp  = NTILES / nsplit;
  const int kt0   = split * ntsp;
  const int ql    = lane & 31;
  const int hi    = lane >> 5;

  f16x8 qf[16];
  {
    const _Float16* qrow = Q + ((size_t)b * SEQ + q0 + w * 32 + ql) * DD;
#pragma unroll
    for (int ks = 0; ks < 16; ++ks)
      qf[ks] = *(const f16x8*)(qrow + ks * 16 + hi * 8);
  }

  const char* Kb = (const char*)(K + (size_t)b * SEQ * DD);
  const char* Vb = (const char*)(VT + (size_t)b * NTILES * (DD * KVBLK));

  auto STAGE_K = [&](int ktAbs) {
    const char* kg = Kb + (size_t)ktAbs * (KVBLK * DD) * 2;
    char* kl = (char*)&Ks[0];
#pragma unroll
    for (int i = 0; i < 4; ++i) {
      int off = i * 8192 + t * 16;
      __builtin_amdgcn_global_load_lds((const void*)(kg + off), (void*)(kl + off),
                                       16, 0, 0);
    }
  };
  auto STAGE_V = [&](int ktAbs, int buf) {
    const char* vg = Vb + (size_t)ktAbs * (DD * KVBLK) * 2;
    char* vl = (char*)&Vt[buf][0];
#pragma unroll
    for (int i = 0; i < 4; ++i) {
      int off = i * 8192 + t * 16;
      __builtin_amdgcn_global_load_lds((const void*)(vg + off), (void*)(vl + off),
                                       16, 0, 0);
    }
  };

  f32x16 cacc[8];
#pragma unroll
  for (int i = 0; i < 8; ++i)
#pragma unroll
    for (int r = 0; r < 16; ++r) cacc[i][r] = 0.f;
  float mrun = -1e30f, lrun = 0.f;

  STAGE_V(kt0, 0);
  STAGE_K(kt0);
  __syncthreads();

  int cur = 0;
  for (int kt = 0; kt < ntsp; ++kt) {
    const bool pre = (kt + 1 < ntsp);
    if (pre) STAGE_V(kt0 + kt + 1, cur ^ 1);

    const char* KsC = (const char*)&Ks[0];
    const char* VtC = (const char*)&Vt[cur][0];
    f16x8 pa0, pa1;

    // ================= S^T tile 0 (kv rows 0..31) =================
    f32x16 sc;
#pragma unroll
    for (int r = 0; r < 16; ++r) sc[r] = 0.f;
    __builtin_amdgcn_s_setprio(1);
#pragma unroll
    for (int ks = 0; ks < 16; ++ks) {
      f16x8 kf = *(const f16x8*)(KsC + (ql << 9) + (((ks * 2 + hi) ^ ql) << 4));
      sc = __builtin_amdgcn_mfma_f32_32x32x16_f16(kf, qf[ks], sc, 0, 0, 0);
    }
    __builtin_amdgcn_s_setprio(0);

    // ---- softmax tile 0 ----
    {
      float tm = sc[0];
#pragma unroll
      for (int r = 1; r < 16; ++r) tm = fmaxf(tm, sc[r]);
      tm = fmaxf(tm, __shfl_xor(tm, 32));
      if (__any(tm > mrun + 8.f)) {
        float mnew = fmaxf(mrun, tm);
        float scl  = __expf(mrun - mnew);
        if (lane < 32) Lw[w][lane] = scl;
#pragma unroll
        for (int r = 0; r < 16; ++r) {
          float s = Lw[w][(r & 3) + 8 * (r >> 2) + 4 * hi];
#pragma unroll
          for (int dt = 0; dt < 8; ++dt) cacc[dt][r] *= s;
        }
        lrun *= scl;
        mrun = mnew;
      }
      float ps = 0.f;
#pragma unroll
      for (int r = 0; r < 16; ++r) {
        float p = __expf(sc[r] - mrun);
        sc[r] = p; ps += p;
      }
      ps += __shfl_xor(ps, 32);
      lrun += ps;
#pragma unroll
      for (int h = 0; h < 2; ++h) {
        const int rb = h * 8;
        unsigned x1 = __builtin_bit_cast(unsigned,
            __builtin_amdgcn_cvt_pkrtz(sc[rb + 0], sc[rb + 1]));
        unsigned y1 = __builtin_bit_cast(unsigned,
            __builtin_amdgcn_cvt_pkrtz(sc[rb + 4], sc[rb + 5]));
        unsigned x2 = __builtin_bit_cast(unsigned,
            __builtin_amdgcn_cvt_pkrtz(sc[rb + 2], sc[rb + 3]));
        unsigned y2 = __builtin_bit_cast(unsigned,
            __builtin_amdgcn_cvt_pkrtz(sc[rb + 6], sc[rb + 7]));
        asm volatile("v_permlane32_swap_b32 %0, %1" : "+v"(x1), "+v"(y1));
        asm volatile("v_permlane32_swap_b32 %0, %1" : "+v"(x2), "+v"(y2));
        union { unsigned u[4]; f16x8 v; } pu;
        pu.u[0] = x1; pu.u[1] = x2; pu.u[2] = y1; pu.u[3] = y2;
        if (h == 0) pa0 = pu.v; else pa1 = pu.v;
      }
    }

    // ---- PV half 0 : st 0,1 (kv rows 0..31) ----
    __builtin_amdgcn_s_setprio(1);
#pragma unroll
    for (int dt = 0; dt < 8; ++dt) {
      const char* vrow = VtC + ((dt * 32 + ql) << 7);
      f16x8 v0 = *(const f16x8*)(vrow + (((0 * 2 + hi) ^ (ql & 7)) << 4));
      f16x8 v1 = *(const f16x8*)(vrow + (((1 * 2 + hi) ^ (ql & 7)) << 4));
      cacc[dt] = __builtin_amdgcn_mfma_f32_32x32x16_f16(pa0, v0, cacc[dt], 0, 0, 0);
      cacc[dt] = __builtin_amdgcn_mfma_f32_32x32x16_f16(pa1, v1, cacc[dt], 0, 0, 0);
    }
    __builtin_amdgcn_s_setprio(0);

    // ================= S^T tile 1 (kv rows 32..63) =================
#pragma unroll
    for (int r = 0; r < 16; ++r) sc[r] = 0.f;
    __builtin_amdgcn_s_setprio(1);
#pragma unroll
    for (int ks = 0; ks < 16; ++ks) {
      f16x8 kf = *(const f16x8*)(KsC + ((32 + ql) << 9) + (((ks * 2 + hi) ^ ql) << 4));
      sc = __builtin_amdgcn_mfma_f32_32x32x16_f16(kf, qf[ks], sc, 0, 0, 0);
    }
    __builtin_amdgcn_s_setprio(0);

    // all K reads of this tile consumed -> safe to restage Ks
    __builtin_amdgcn_s_barrier();
    if (pre) STAGE_K(kt0 + kt + 1);      // lands during softmax + PV

    // ---- softmax tile 1 (rescale covers half-0 already in cacc) ----
    {
      float tm = sc[0];
#pragma unroll
      for (int r = 1; r < 16; ++r) tm = fmaxf(tm, sc[r]);
      tm = fmaxf(tm, __shfl_xor(tm, 32));
      if (__any(tm > mrun + 8.f)) {
        float mnew = fmaxf(mrun, tm);
        float scl  = __expf(mrun - mnew);
        if (lane < 32) Lw[w][lane] = scl;
#pragma unroll
        for (int r = 0; r < 16; ++r) {
          float s = Lw[w][(r & 3) + 8 * (r >> 2) + 4 * hi];
#pragma unroll
          for (int dt = 0; dt < 8; ++dt) cacc[dt][r] *= s;
        }
        lrun *= scl;
        mrun = mnew;
      }
      float ps = 0.f;
#pragma unroll
      for (int r = 0; r < 16; ++r) {
        float p = __expf(sc[r] - mrun);
        sc[r] = p; ps += p;
      }
      ps += __shfl_xor(ps, 32);
      lrun += ps;
#pragma unroll
      for (int h = 0; h < 2; ++h) {
        const int rb = h * 8;
        unsigned x1 = __builtin_bit_cast(unsigned,
            __builtin_amdgcn_cvt_pkrtz(sc[rb + 0], sc[rb + 1]));
        unsigned y1 = __builtin_bit_cast(unsigned,
            __builtin_amdgcn_cvt_pkrtz(sc[rb + 4], sc[rb + 5]));
        unsigned x2 = __builtin_bit_cast(unsigned,
            __builtin_amdgcn_cvt_pkrtz(sc[rb + 2], sc[rb + 3]));
        unsigned y2 = __builtin_bit_cast(unsigned,
            __builtin_amdgcn_cvt_pkrtz(sc[rb + 6], sc[rb + 7]));
        asm volatile("v_permlane32_swap_b32 %0, %1" : "+v"(x1), "+v"(y1));
        asm volatile("v_permlane32_swap_b32 %0, %1" : "+v"(x2), "+v"(y2));
        union { unsigned u[4]; f16x8 v; } pu;
        pu.u[0] = x1; pu.u[1] = x2; pu.u[2] = y1; pu.u[3] = y2;
        if (h == 0) pa0 = pu.v; else pa1 = pu.v;
      }
    }

    // ---- PV half 1 : st 2,3 (kv rows 32..63) ----
    __builtin_amdgcn_s_setprio(1);
#pragma unroll
    for (int dt = 0; dt < 8; ++dt) {
      const char* vrow = VtC + ((dt * 32 + ql) << 7);
      f16x8 v0 = *(const f16x8*)(vrow + (((2 * 2 + hi) ^ (ql & 7)) << 4));
      f16x8 v1 = *(const f16x8*)(vrow + (((3 * 2 + hi) ^ (ql & 7)) << 4));
      cacc[dt] = __builtin_amdgcn_mfma_f32_32x32x16_f16(pa0, v0, cacc[dt], 0, 0, 0);
      cacc[dt] = __builtin_amdgcn_mfma_f32_32x32x16_f16(pa1, v1, cacc[dt], 0, 0, 0);
    }
    __builtin_amdgcn_s_setprio(0);

    __syncthreads();   // drains vmcnt: K(t+1) + V(t+1) landed
    cur ^= 1;
  }

  // ---- epilogue: NORMALIZED partial ctx (f16) + m/l -----------------------
  if (lane < 32) {
    const size_t R = (size_t)b * SEQ + q0 + w * 32 + lane;
    Mp[(size_t)split * RROWS + R] = mrun;
    Lp[(size_t)split * RROWS + R] = lrun;
    Lw[w][lane] = lrun;
  }
#pragma unroll
  for (int r = 0; r < 16; ++r) {
    const int q = (r & 3) + 8 * (r >> 2) + 4 * hi;
    const float inv = 1.0f / Lw[w][q];
    const size_t R = (size_t)b * SEQ + q0 + w * 32 + q;
#pragma unroll
    for (int dt = 0; dt < 8; ++dt)
      Op[((size_t)split * RROWS + R) * DD + dt * 32 + ql] =
          (_Float16)(cacc[dt][r] * inv);
  }
}

// ---------------------------------------------------------------------------
// Combine nsplit NORMALIZED partials.
// ---------------------------------------------------------------------------
__global__ __launch_bounds__(256) void attn_combine_kernel(
    const _Float16* __restrict__ Op, const float* __restrict__ Mp,
    const float* __restrict__ Lp, _Float16* __restrict__ ctx, int nsplit)
{
  const int lane = threadIdx.x & 63;
  const int w    = threadIdx.x >> 6;
  const size_t R = (size_t)blockIdx.x * 4 + w;
  float ms = -1e30f;
  for (int s = 0; s < nsplit; ++s) ms = fmaxf(ms, Mp[(size_t)s * RROWS + R]);
  float wgt[4], ctot = 0.f;
  for (int s = 0; s < nsplit; ++s) {
    float c = __expf(Mp[(size_t)s * RROWS + R] - ms) * Lp[(size_t)s * RROWS + R];
    wgt[s] = c; ctot += c;
  }
  float inv = 1.0f / ctot;
  float acc[4] = {0.f, 0.f, 0.f, 0.f};
  for (int s = 0; s < nsplit; ++s) {
    f16x4 o = *(const f16x4*)&Op[((size_t)s * RROWS + R) * DD + lane * 4];
#pragma unroll
    for (int i = 0; i < 4; ++i) acc[i] += wgt[s] * (float)o[i];
  }
  f16x4 o;
#pragma unroll
  for (int i = 0; i < 4; ++i) o[i] = (_Float16)(acc[i] * inv);
  *(f16x4*)&ctx[R * DD + lane * 4] = o;
}

// ---------------------------------------------------------------------------
// LayerNorm over last dim (256). One wave per row, 4 rows per block.
// ---------------------------------------------------------------------------
__global__ __launch_bounds__(256) void ln_kernel(
    const float* __restrict__ H, const float* __restrict__ g,
    const float* __restrict__ b, float* __restrict__ out)
{
  const int lane = threadIdx.x & 63;
  const int w    = threadIdx.x >> 6;
  const int r    = blockIdx.x * 4 + w;
  const size_t rowoff = (size_t)r * DD;
  float4 h4 = *(const float4*)&H[rowoff + lane * 4];
  float s = h4.x + h4.y + h4.z + h4.w;
#pragma unroll
  for (int m = 1; m < 64; m <<= 1) s += __shfl_xor(s, m, 64);
  float mu = s * (1.0f / 256.0f);
  float dx = h4.x - mu, dy = h4.y - mu, dz = h4.z - mu, dw = h4.w - mu;
  float v = dx*dx + dy*dy + dz*dz + dw*dw;
#pragma unroll
  for (int m = 1; m < 64; m <<= 1) v += __shfl_xor(v, m, 64);
  float rs = rsqrtf(v * (1.0f / 256.0f) + 1e-5f);
  float4 g4 = *(const float4*)&g[lane * 4];
  float4 b4 = *(const float4*)&b[lane * 4];
  float4 o;
  o.x = dx * rs * g4.x + b4.x;
  o.y = dy * rs * g4.y + b4.y;
  o.z = dz * rs * g4.z + b4.z;
  o.w = dw * rs * g4.w + b4.w;
  *(float4*)&out[rowoff + lane * 4] = o;
}

// ---------------------------------------------------------------------------
extern "C" void kernel_launch(void* const* d_in, const int* in_sizes, int n_in,
                              void* d_out, int out_size, void* d_ws, size_t ws_size,
                              hipStream_t stream) {
  const float* x  = (const float*)d_in[0];
  const float* Wq = (const float*)d_in[1];
  const float* bq = (const float*)d_in[2];
  const float* Wk = (const float*)d_in[3];
  const float* bk = (const float*)d_in[4];
  const float* Wv = (const float*)d_in[5];
  const float* bv = (const float*)d_in[6];
  const float* Wd = (const float*)d_in[7];
  const float* bd = (const float*)d_in[8];
  const float* g  = (const float*)d_in[9];
  const float* b  = (const float*)d_in[10];
  float* out = (float*)d_out;

  const int nsplit = (ws_size >= (58ull << 20)) ? 4 : 2;

  char* W = (char*)d_ws;
  _Float16* Qh   = (_Float16*)(W + (0ull  << 20));   //  8 MB; later ctx
  _Float16* Kh   = (_Float16*)(W + (8ull  << 20));   //  8 MB, swizzled ^r&31
  _Float16* VtG  = (_Float16*)(W + (16ull << 20));   //  8 MB, tiled+swizzled
  _Float16* Op   = (_Float16*)(W + (24ull << 20));   //  8*nsplit MB
  float*    Hf   = (float*)(W + (24ull << 20));      // 16 MB, overlays Op
  size_t tail = (24ull << 20) + (size_t)nsplit * (8ull << 20);
  float*    Mp   = (float*)(W + tail);
  float*    Lp   = Mp + (size_t)nsplit * RROWS;
  _Float16* Wh   = (_Float16*)(Lp + (size_t)nsplit * RROWS);   // 512 KB
  _Float16* ctxh = Qh;

  cast_w_kernel<<<dim3(32, 4), 256, 0, stream>>>(Wq, Wk, Wv, Wd, Wh);

  dim3 gg(RROWS / 64, DD / 128);   // (256, 2)
  gemm_qkv_kernel<<<gg, 256, 0, stream>>>(x, Wh, bq, bk, bv, Qh, Kh, VtG);

  // grid: 8 q-tiles x nsplit x 8 batches (= 256 blocks at nsplit=4)
  attn_partial_kernel<<<dim3((SEQ / QBLK) * nsplit * NB), 512, 0, stream>>>(
      Qh, Kh, VtG, Op, Mp, Lp, nsplit);
  attn_combine_kernel<<<RROWS / 4, 256, 0, stream>>>(Op, Mp, Lp, ctxh, nsplit);

  gemm_out_kernel<<<gg, 256, 0, stream>>>(ctxh, Wh + 3 * 65536, bd, x, Hf);

  ln_kernel<<<RROWS / 4, 256, 0, stream>>>(Hf, g, b, out);
}